// Round 1
// baseline (1514.339 us; speedup 1.0000x reference)
//
#include <hip/hip_runtime.h>
#include <hip/hip_bf16.h>

// Problem constants
#define B 2
#define C 512
#define NTOK 4096          // d*w*hs = 16*16*16
#define GROUPS 32
#define CPG 16             // channels per group
#define CTX 1024
#define CDIM 768
#define NH 8
#define HD 64
#define INNER 512          // NH*HD
#define EPS 1e-5f
#define QROWS 8

__inline__ __device__ float waveReduceSum(float v) {
    #pragma unroll
    for (int o = 32; o > 0; o >>= 1) v += __shfl_xor(v, o);
    return v;
}

// ---------------------------------------------------------------------------
// Kernel 1: GroupNorm statistics. One block per (b, group).
// A group's data is a contiguous 16*4096 = 65536-float block of x.
__global__ void gn_stats_kernel(const float* __restrict__ x, float* __restrict__ stats) {
    int bg = blockIdx.x;            // 0..63
    int b = bg >> 5, g = bg & 31;
    const float* base = x + ((size_t)(b * C + g * CPG)) * NTOK;
    float s = 0.f, ss = 0.f;
    for (int i = threadIdx.x; i < CPG * NTOK; i += 256) {
        float v = base[i];
        s += v; ss += v * v;
    }
    s = waveReduceSum(s);
    ss = waveReduceSum(ss);
    __shared__ float ls[2][4];
    int wv = threadIdx.x >> 6, ln = threadIdx.x & 63;
    if (ln == 0) { ls[0][wv] = s; ls[1][wv] = ss; }
    __syncthreads();
    if (threadIdx.x == 0) {
        float S = ls[0][0] + ls[0][1] + ls[0][2] + ls[0][3];
        float SS = ls[1][0] + ls[1][1] + ls[1][2] + ls[1][3];
        float mu = S / (float)(CPG * NTOK);
        float var = SS / (float)(CPG * NTOK) - mu * mu;
        stats[bg] = mu;
        stats[64 + bg] = rsqrtf(var + EPS);
    }
}

// ---------------------------------------------------------------------------
// Kernel 2: apply GroupNorm + transpose to xn[b][t][c] (token-major).
// 32x32 tile transpose through LDS; coalesced load over t, coalesced store over c.
__global__ void gn_apply_kernel(const float* __restrict__ x, const float* __restrict__ stats,
                                const float* __restrict__ gamma, const float* __restrict__ beta,
                                float* __restrict__ xn) {
    __shared__ float tile[32][33];
    int b = blockIdx.z;
    int c0 = blockIdx.y * 32;
    int t0 = blockIdx.x * 32;
    int tt = threadIdx.x & 31, cr = threadIdx.x >> 5;   // cr in 0..7
    #pragma unroll
    for (int i = 0; i < 4; ++i) {
        int c = c0 + cr + 8 * i;
        float mu = stats[b * 32 + (c >> 4)];
        float rs = stats[64 + b * 32 + (c >> 4)];
        float v = x[((size_t)(b * C + c)) * NTOK + t0 + tt];
        tile[cr + 8 * i][tt] = (v - mu) * rs * gamma[c] + beta[c];
    }
    __syncthreads();
    #pragma unroll
    for (int i = 0; i < 4; ++i) {
        int t = t0 + cr + 8 * i;
        int c = c0 + tt;
        xn[((size_t)b * NTOK + t) * C + c] = tile[tt][cr + 8 * i];
    }
}

// ---------------------------------------------------------------------------
// Kernel 3: generic fp32 tiled GEMM  Cm[M,Nn] = A[M,K] @ Bw[K,Nn]
// 32x32 tiles, 256 threads, each thread computes 4 outputs.
__global__ void gemm_kernel(const float* __restrict__ A, const float* __restrict__ Bw,
                            float* __restrict__ Cm, int M, int K, int Nn) {
    __shared__ float As[32][33], Bs[32][33];
    int m0 = blockIdx.x * 32, n0 = blockIdx.y * 32;
    int tx = threadIdx.x & 31, ty = threadIdx.x >> 5;
    float acc[4] = {0.f, 0.f, 0.f, 0.f};
    for (int k0 = 0; k0 < K; k0 += 32) {
        #pragma unroll
        for (int i = 0; i < 4; ++i) {
            As[ty + 8 * i][tx] = A[(size_t)(m0 + ty + 8 * i) * K + k0 + tx];
            Bs[ty + 8 * i][tx] = Bw[(size_t)(k0 + ty + 8 * i) * Nn + n0 + tx];
        }
        __syncthreads();
        #pragma unroll 8
        for (int kk = 0; kk < 32; ++kk) {
            float bv = Bs[kk][tx];
            #pragma unroll
            for (int i = 0; i < 4; ++i) acc[i] += As[ty + 8 * i][kk] * bv;
        }
        __syncthreads();
    }
    #pragma unroll
    for (int i = 0; i < 4; ++i)
        Cm[(size_t)(m0 + ty + 8 * i) * Nn + n0 + tx] = acc[i];
}

// ---------------------------------------------------------------------------
// Kernel 4: attention. One block per (b, h, 8 q-rows).
// Scores (8x1024) live in LDS; K/V staged in 64x65-padded LDS chunks.
__global__ void attn_kernel(const float* __restrict__ q, const float* __restrict__ k,
                            const float* __restrict__ v, float* __restrict__ ao) {
    __shared__ float sc[QROWS][CTX];      // 32 KB
    __shared__ float qs[QROWS][HD];       // 2 KB
    __shared__ float kv[64][HD + 1];      // 16.6 KB
    int blk = blockIdx.x;
    int qc = blk & 511;                   // NTOK/QROWS = 512
    int h = (blk >> 9) & 7;
    int b = blk >> 12;
    int t0 = qc * QROWS;
    int tid = threadIdx.x;

    for (int i = tid; i < QROWS * HD; i += 256) {
        int r = i >> 6, d = i & 63;
        qs[r][d] = q[((size_t)b * NTOK + t0 + r) * INNER + h * HD + d];
    }
    __syncthreads();

    const float scale = 0.125f;           // HD^-0.5
    for (int key0 = 0; key0 < CTX; key0 += 64) {
        for (int i = tid; i < 64 * HD; i += 256) {
            int kk = i >> 6, d = i & 63;
            kv[kk][d] = k[((size_t)b * CTX + key0 + kk) * INNER + h * HD + d];
        }
        __syncthreads();
        #pragma unroll
        for (int i = 0; i < 2; ++i) {
            int idx = tid + i * 256;
            int r = idx >> 6, kk = idx & 63;
            float s = 0.f;
            #pragma unroll 16
            for (int d = 0; d < HD; ++d) s += qs[r][d] * kv[kk][d];
            sc[r][key0 + kk] = s * scale;
        }
        __syncthreads();
    }

    // softmax: wave w handles rows 2w, 2w+1
    int wv = tid >> 6, ln = tid & 63;
    for (int r = 2 * wv; r < 2 * wv + 2; ++r) {
        float m = -1e30f;
        #pragma unroll
        for (int j = 0; j < CTX / 64; ++j) m = fmaxf(m, sc[r][ln + 64 * j]);
        #pragma unroll
        for (int o = 32; o > 0; o >>= 1) m = fmaxf(m, __shfl_xor(m, o));
        float sum = 0.f;
        #pragma unroll
        for (int j = 0; j < CTX / 64; ++j) {
            float e = __expf(sc[r][ln + 64 * j] - m);
            sc[r][ln + 64 * j] = e;
            sum += e;
        }
        #pragma unroll
        for (int o = 32; o > 0; o >>= 1) sum += __shfl_xor(sum, o);
        float inv = 1.0f / sum;
        #pragma unroll
        for (int j = 0; j < CTX / 64; ++j) sc[r][ln + 64 * j] *= inv;
    }
    __syncthreads();

    // PV: thread owns (r0, dd) and (r0+4, dd)
    float acc0 = 0.f, acc1 = 0.f;
    int r0 = tid >> 6;
    int dd = tid & 63;
    for (int key0 = 0; key0 < CTX; key0 += 64) {
        for (int i = tid; i < 64 * HD; i += 256) {
            int kk = i >> 6, d = i & 63;
            kv[kk][d] = v[((size_t)b * CTX + key0 + kk) * INNER + h * HD + d];
        }
        __syncthreads();
        #pragma unroll 16
        for (int kk = 0; kk < 64; ++kk) {
            float vv = kv[kk][dd];
            acc0 += sc[r0][key0 + kk] * vv;
            acc1 += sc[r0 + 4][key0 + kk] * vv;
        }
        __syncthreads();
    }
    ao[((size_t)b * NTOK + t0 + r0) * INNER + h * HD + dd] = acc0;
    ao[((size_t)b * NTOK + t0 + r0 + 4) * INNER + h * HD + dd] = acc1;
}

// ---------------------------------------------------------------------------
// Kernel 5: O-projection GEMM + bias + residual + transpose back to [b][c][t].
__global__ void gemm_out_kernel(const float* __restrict__ A, const float* __restrict__ Bw,
                                const float* __restrict__ bo, const float* __restrict__ x,
                                float* __restrict__ out) {
    __shared__ float As[32][33], Bs[32][33], Ct[32][33];
    int m0 = blockIdx.x * 32, n0 = blockIdx.y * 32;   // m over (b,t), n over c
    int tx = threadIdx.x & 31, ty = threadIdx.x >> 5;
    float acc[4] = {0.f, 0.f, 0.f, 0.f};
    for (int k0 = 0; k0 < INNER; k0 += 32) {
        #pragma unroll
        for (int i = 0; i < 4; ++i) {
            As[ty + 8 * i][tx] = A[(size_t)(m0 + ty + 8 * i) * INNER + k0 + tx];
            Bs[ty + 8 * i][tx] = Bw[(size_t)(k0 + ty + 8 * i) * C + n0 + tx];
        }
        __syncthreads();
        #pragma unroll 8
        for (int kk = 0; kk < 32; ++kk) {
            float bv = Bs[kk][tx];
            #pragma unroll
            for (int i = 0; i < 4; ++i) acc[i] += As[ty + 8 * i][kk] * bv;
        }
        __syncthreads();
    }
    #pragma unroll
    for (int i = 0; i < 4; ++i) Ct[ty + 8 * i][tx] = acc[i];
    __syncthreads();
    int b = m0 / NTOK;
    int tbase = m0 % NTOK;
    #pragma unroll
    for (int i = 0; i < 4; ++i) {
        int c = n0 + ty + 8 * i;
        int t = tbase + tx;
        size_t oidx = ((size_t)(b * C + c)) * NTOK + t;
        out[oidx] = Ct[tx][ty + 8 * i] + bo[c] + x[oidx];
    }
}

// ---------------------------------------------------------------------------
extern "C" void kernel_launch(void* const* d_in, const int* in_sizes, int n_in,
                              void* d_out, int out_size, void* d_ws, size_t ws_size,
                              hipStream_t stream) {
    const float* x       = (const float*)d_in[0];
    const float* context = (const float*)d_in[1];
    const float* gamma   = (const float*)d_in[2];
    const float* beta    = (const float*)d_in[3];
    const float* Wq      = (const float*)d_in[4];
    const float* Wk      = (const float*)d_in[5];
    const float* Wv      = (const float*)d_in[6];
    const float* Wo      = (const float*)d_in[7];
    const float* bo      = (const float*)d_in[8];
    float* out = (float*)d_out;

    float* ws    = (float*)d_ws;
    float* stats = ws;                                  // 128 floats used
    float* xn    = ws + 256;                            // [2,4096,512]
    float* qb    = xn + (size_t)B * NTOK * INNER;       // [2,4096,512]
    float* kb    = qb + (size_t)B * NTOK * INNER;       // [2,1024,512]
    float* vb    = kb + (size_t)B * CTX * INNER;        // [2,1024,512]
    float* ao    = vb + (size_t)B * CTX * INNER;        // [2,4096,512]

    hipLaunchKernelGGL(gn_stats_kernel, dim3(B * GROUPS), dim3(256), 0, stream, x, stats);
    hipLaunchKernelGGL(gn_apply_kernel, dim3(NTOK / 32, C / 32, B), dim3(256), 0, stream,
                       x, stats, gamma, beta, xn);
    hipLaunchKernelGGL(gemm_kernel, dim3((B * NTOK) / 32, INNER / 32), dim3(256), 0, stream,
                       xn, Wq, qb, B * NTOK, C, INNER);
    hipLaunchKernelGGL(gemm_kernel, dim3((B * CTX) / 32, INNER / 32), dim3(256), 0, stream,
                       context, Wk, kb, B * CTX, CDIM, INNER);
    hipLaunchKernelGGL(gemm_kernel, dim3((B * CTX) / 32, INNER / 32), dim3(256), 0, stream,
                       context, Wv, vb, B * CTX, CDIM, INNER);
    hipLaunchKernelGGL(attn_kernel, dim3(B * NH * (NTOK / QROWS)), dim3(256), 0, stream,
                       qb, kb, vb, ao);
    hipLaunchKernelGGL(gemm_out_kernel, dim3((B * NTOK) / 32, C / 32), dim3(256), 0, stream,
                       ao, Wo, bo, x, out);
}

// Round 2
// 310.600 us; speedup vs baseline: 4.8755x; 4.8755x over previous
//
#include <hip/hip_runtime.h>
#include <hip/hip_bf16.h>

#define B 2
#define C 512
#define NTOK 4096          // d*w*hs
#define GROUPS 32
#define CPG 16
#define CTX 1024
#define CDIM 768
#define NH 8
#define HD 64
#define INNER 512
#define EPS 1e-5f

typedef unsigned short bf16_t;
typedef __attribute__((ext_vector_type(8))) short bf16x8;   // 8 bf16 = 4 VGPRs (MFMA A/B frag)
typedef __attribute__((ext_vector_type(4))) float f32x4;    // MFMA C/D frag

__device__ __forceinline__ bf16_t f2b(float f) {
    unsigned u = __float_as_uint(f);
    u += 0x7fffu + ((u >> 16) & 1u);          // RNE
    return (bf16_t)(u >> 16);
}

// ---------------------------------------------------------------------------
// GroupNorm statistics: one block per (b, group); group = contiguous 64K floats.
__global__ __launch_bounds__(256) void gn_stats_kernel(const float* __restrict__ x,
                                                       float* __restrict__ stats) {
    int bg = blockIdx.x;
    int b = bg >> 5, g = bg & 31;
    const float* base = x + ((size_t)(b * C + g * CPG)) * NTOK;
    float s = 0.f, ss = 0.f;
    for (int i = threadIdx.x; i < CPG * NTOK; i += 256) {
        float v = base[i];
        s += v; ss += v * v;
    }
    #pragma unroll
    for (int o = 32; o > 0; o >>= 1) { s += __shfl_xor(s, o); ss += __shfl_xor(ss, o); }
    __shared__ float ls[2][4];
    int wv = threadIdx.x >> 6, ln = threadIdx.x & 63;
    if (ln == 0) { ls[0][wv] = s; ls[1][wv] = ss; }
    __syncthreads();
    if (threadIdx.x == 0) {
        float S = ls[0][0] + ls[0][1] + ls[0][2] + ls[0][3];
        float SS = ls[1][0] + ls[1][1] + ls[1][2] + ls[1][3];
        float mu = S / (float)(CPG * NTOK);
        float var = SS / (float)(CPG * NTOK) - mu * mu;
        stats[bg] = mu;
        stats[64 + bg] = rsqrtf(var + EPS);
    }
}

// ---------------------------------------------------------------------------
// Apply GroupNorm + transpose to bf16 xn[b][t][c].
__global__ __launch_bounds__(256) void gn_apply_kernel(const float* __restrict__ x,
                                                       const float* __restrict__ stats,
                                                       const float* __restrict__ gamma,
                                                       const float* __restrict__ beta,
                                                       bf16_t* __restrict__ xn) {
    __shared__ float tile[32][33];
    int b = blockIdx.z;
    int c0 = blockIdx.y * 32;
    int t0 = blockIdx.x * 32;
    int tt = threadIdx.x & 31, cr = threadIdx.x >> 5;
    #pragma unroll
    for (int i = 0; i < 4; ++i) {
        int c = c0 + cr + 8 * i;
        float mu = stats[b * 32 + (c >> 4)];
        float rs = stats[64 + b * 32 + (c >> 4)];
        float v = x[((size_t)(b * C + c)) * NTOK + t0 + tt];
        tile[cr + 8 * i][tt] = (v - mu) * rs * gamma[c] + beta[c];
    }
    __syncthreads();
    #pragma unroll
    for (int i = 0; i < 4; ++i) {
        int t = t0 + cr + 8 * i;
        int c = c0 + tt;
        xn[((size_t)b * NTOK + t) * C + c] = f2b(tile[tt][cr + 8 * i]);
    }
}

// ---------------------------------------------------------------------------
// Weight transpose+cast: out[n][k] (bf16, row stride ldo) = in[k][n] (fp32).
__global__ __launch_bounds__(256) void wcast_kernel(const float* __restrict__ in,
                                                    bf16_t* __restrict__ out,
                                                    int K, int N, int ldo) {
    __shared__ float t[32][33];
    int k0 = blockIdx.x * 32, n0 = blockIdx.y * 32;
    int xx = threadIdx.x & 31, yy = threadIdx.x >> 5;
    #pragma unroll
    for (int i = 0; i < 4; ++i)
        t[yy + 8 * i][xx] = in[(size_t)(k0 + yy + 8 * i) * N + n0 + xx];
    __syncthreads();
    #pragma unroll
    for (int i = 0; i < 4; ++i)
        out[(size_t)(n0 + yy + 8 * i) * ldo + k0 + xx] = f2b(t[xx][yy + 8 * i]);
}

// context fp32 -> bf16, same layout.
__global__ __launch_bounds__(256) void castctx_kernel(const float* __restrict__ in,
                                                      bf16_t* __restrict__ out) {
    int i = (blockIdx.x * 256 + threadIdx.x) * 4;
    float4 v = *(const float4*)&in[i];
    out[i + 0] = f2b(v.x); out[i + 1] = f2b(v.y);
    out[i + 2] = f2b(v.z); out[i + 3] = f2b(v.w);
}

// ---------------------------------------------------------------------------
// MFMA GEMM, 128x128 tile, 4 waves (2x2), BK=32. C = A[M][K] @ Bt[N][K]^T.
// Epilogue scatters bf16 to head-major [bidx][h][seq][d]; cols >= 512 go to outV.
__global__ __launch_bounds__(256) void gemm_qkv_kernel(
    const bf16_t* __restrict__ A, const bf16_t* __restrict__ Bt,
    bf16_t* __restrict__ outK, bf16_t* __restrict__ outV,
    int K, int seqshift) {
    __shared__ __align__(16) bf16_t As[128][40];   // 40-short rows: 80B, 16B-aligned frag reads
    __shared__ __align__(16) bf16_t Bs[128][40];
    const int tid = threadIdx.x;
    const int l = tid & 63, w = tid >> 6;
    const int wr = w >> 1, wc = w & 1;
    const int lg = l >> 4, lr = l & 15;
    const int m0 = blockIdx.x * 128, n0 = blockIdx.y * 128;
    const int rowA = tid >> 2, c8 = (tid & 3) * 8;
    const int rowB = rowA + 64;
    f32x4 acc[4][4] = {};
    for (int k0 = 0; k0 < K; k0 += 32) {
        *(float4*)&As[rowA][c8] = *(const float4*)&A[(size_t)(m0 + rowA) * K + k0 + c8];
        *(float4*)&As[rowB][c8] = *(const float4*)&A[(size_t)(m0 + rowB) * K + k0 + c8];
        *(float4*)&Bs[rowA][c8] = *(const float4*)&Bt[(size_t)(n0 + rowA) * K + k0 + c8];
        *(float4*)&Bs[rowB][c8] = *(const float4*)&Bt[(size_t)(n0 + rowB) * K + k0 + c8];
        __syncthreads();
        bf16x8 af[4], bfr[4];
        #pragma unroll
        for (int mi = 0; mi < 4; ++mi) af[mi] = *(bf16x8*)&As[wr * 64 + mi * 16 + lr][lg * 8];
        #pragma unroll
        for (int ni = 0; ni < 4; ++ni) bfr[ni] = *(bf16x8*)&Bs[wc * 64 + ni * 16 + lr][lg * 8];
        #pragma unroll
        for (int mi = 0; mi < 4; ++mi)
            #pragma unroll
            for (int ni = 0; ni < 4; ++ni)
                acc[mi][ni] = __builtin_amdgcn_mfma_f32_16x16x32_bf16(af[mi], bfr[ni], acc[mi][ni], 0, 0, 0);
        __syncthreads();
    }
    const int seqmask = (1 << seqshift) - 1;
    #pragma unroll
    for (int ni = 0; ni < 4; ++ni) {
        int n = n0 + wc * 64 + ni * 16 + lr;
        bf16_t* dst = (n < INNER) ? outK : outV;
        int nn = n & (INNER - 1);
        int h = nn >> 6, dd = nn & 63;
        #pragma unroll
        for (int mi = 0; mi < 4; ++mi) {
            #pragma unroll
            for (int r = 0; r < 4; ++r) {
                int m = m0 + wr * 64 + mi * 16 + lg * 4 + r;
                int bidx = m >> seqshift, seq = m & seqmask;
                size_t o = ((((size_t)(bidx * NH + h)) << seqshift) + seq) * HD + dd;
                dst[o] = f2b(acc[mi][ni][r]);
            }
        }
    }
}

// O-projection GEMM (K=512) + bias + residual + transpose to fp32 out[b][c][t].
__global__ __launch_bounds__(256) void gemm_o_kernel(
    const bf16_t* __restrict__ A, const bf16_t* __restrict__ Bt,
    const float* __restrict__ bo, const float* __restrict__ x,
    float* __restrict__ out) {
    __shared__ __align__(16) bf16_t As[128][40];
    __shared__ __align__(16) bf16_t Bs[128][40];
    const int tid = threadIdx.x;
    const int l = tid & 63, w = tid >> 6;
    const int wr = w >> 1, wc = w & 1;
    const int lg = l >> 4, lr = l & 15;
    const int m0 = blockIdx.x * 128, n0 = blockIdx.y * 128;
    const int rowA = tid >> 2, c8 = (tid & 3) * 8;
    const int rowB = rowA + 64;
    f32x4 acc[4][4] = {};
    for (int k0 = 0; k0 < INNER; k0 += 32) {
        *(float4*)&As[rowA][c8] = *(const float4*)&A[(size_t)(m0 + rowA) * INNER + k0 + c8];
        *(float4*)&As[rowB][c8] = *(const float4*)&A[(size_t)(m0 + rowB) * INNER + k0 + c8];
        *(float4*)&Bs[rowA][c8] = *(const float4*)&Bt[(size_t)(n0 + rowA) * INNER + k0 + c8];
        *(float4*)&Bs[rowB][c8] = *(const float4*)&Bt[(size_t)(n0 + rowB) * INNER + k0 + c8];
        __syncthreads();
        bf16x8 af[4], bfr[4];
        #pragma unroll
        for (int mi = 0; mi < 4; ++mi) af[mi] = *(bf16x8*)&As[wr * 64 + mi * 16 + lr][lg * 8];
        #pragma unroll
        for (int ni = 0; ni < 4; ++ni) bfr[ni] = *(bf16x8*)&Bs[wc * 64 + ni * 16 + lr][lg * 8];
        #pragma unroll
        for (int mi = 0; mi < 4; ++mi)
            #pragma unroll
            for (int ni = 0; ni < 4; ++ni)
                acc[mi][ni] = __builtin_amdgcn_mfma_f32_16x16x32_bf16(af[mi], bfr[ni], acc[mi][ni], 0, 0, 0);
        __syncthreads();
    }
    #pragma unroll
    for (int mi = 0; mi < 4; ++mi) {
        int mbase = m0 + wr * 64 + mi * 16 + lg * 4;     // 4 consecutive t (regs r=0..3)
        int t = mbase & (NTOK - 1);
        int bb = mbase >> 12;
        #pragma unroll
        for (int ni = 0; ni < 4; ++ni) {
            int cc = n0 + wc * 64 + ni * 16 + lr;
            size_t o = (((size_t)(bb * C + cc)) << 12) + t;
            float4 xr = *(const float4*)&x[o];
            float bias = bo[cc];
            float4 ov;
            ov.x = acc[mi][ni][0] + bias + xr.x;
            ov.y = acc[mi][ni][1] + bias + xr.y;
            ov.z = acc[mi][ni][2] + bias + xr.z;
            ov.w = acc[mi][ni][3] + bias + xr.w;
            *(float4*)&out[o] = ov;
        }
    }
}

// ---------------------------------------------------------------------------
// Flash attention. Block = 4 waves; wave owns 16 Q rows; KV chunks of 64 in LDS.
__global__ __launch_bounds__(256) void attn_kernel(
    const bf16_t* __restrict__ Q, const bf16_t* __restrict__ Kb,
    const bf16_t* __restrict__ Vb, bf16_t* __restrict__ AO) {
    __shared__ __align__(16) bf16_t Ks[64][72];     // [key][d], 144B rows
    __shared__ __align__(16) bf16_t Vs[64][72];     // [d][key] (transposed at stage time)
    __shared__ __align__(16) bf16_t Ps[4][16][72];  // per-wave P tile [row][key]
    const int tid = threadIdx.x;
    const int l = tid & 63, w = tid >> 6;
    const int lg = l >> 4, lr = l & 15;
    const int bh = blockIdx.x >> 6;                 // b*8+h
    const int tile = blockIdx.x & 63;
    const int b = bh >> 3, h = bh & 7;
    const int t0 = tile * 64 + w * 16;

    // Q fragments, reused across all chunks: A-frag row lr, k = ks*32 + lg*8 + j
    const bf16_t* qbase = Q + ((size_t)bh * NTOK + t0 + lr) * HD;
    bf16x8 qf[2];
    qf[0] = *(const bf16x8*)&qbase[lg * 8];
    qf[1] = *(const bf16x8*)&qbase[32 + lg * 8];

    f32x4 acc[4] = {};                              // O cols d = ni*16+lr, rows 4*lg+r
    float mrow[4], lrow[4];
    #pragma unroll
    for (int r = 0; r < 4; ++r) { mrow[r] = -1e30f; lrow[r] = 0.f; }

    const bf16_t* kbase = Kb + (size_t)bh * CTX * HD;
    const bf16_t* vbase = Vb + (size_t)bh * CTX * HD;
    const int srow = tid >> 3, sc8 = (tid & 7) * 8; // staging coords (2 iters: +32 rows)

    for (int key0 = 0; key0 < CTX; key0 += 64) {
        #pragma unroll
        for (int i = 0; i < 2; ++i) {
            int row = srow + i * 32;
            *(float4*)&Ks[row][sc8] = *(const float4*)&kbase[(size_t)(key0 + row) * HD + sc8];
            float4 vv = *(const float4*)&vbase[(size_t)(key0 + row) * HD + sc8];
            const bf16_t* vsp = (const bf16_t*)&vv;
            #pragma unroll
            for (int j = 0; j < 8; ++j) Vs[sc8 + j][row] = vsp[j];  // transpose scatter
        }
        __syncthreads();

        // QK^T: S[16 q-rows][64 keys], B-frag = K^T read from Ks[key][d]
        f32x4 sf[4] = {};
        #pragma unroll
        for (int ni = 0; ni < 4; ++ni) {
            #pragma unroll
            for (int ks = 0; ks < 2; ++ks) {
                bf16x8 kf = *(bf16x8*)&Ks[ni * 16 + lr][ks * 32 + lg * 8];
                sf[ni] = __builtin_amdgcn_mfma_f32_16x16x32_bf16(qf[ks], kf, sf[ni], 0, 0, 0);
            }
        }

        // Online softmax; thread holds rows 4*lg+r, cols ni*16+lr.
        #pragma unroll
        for (int r = 0; r < 4; ++r) {
            float s0 = sf[0][r] * 0.125f, s1 = sf[1][r] * 0.125f;
            float s2 = sf[2][r] * 0.125f, s3 = sf[3][r] * 0.125f;
            float cm = fmaxf(fmaxf(s0, s1), fmaxf(s2, s3));
            cm = fmaxf(cm, __shfl_xor(cm, 1));
            cm = fmaxf(cm, __shfl_xor(cm, 2));
            cm = fmaxf(cm, __shfl_xor(cm, 4));
            cm = fmaxf(cm, __shfl_xor(cm, 8));
            float mn = fmaxf(mrow[r], cm);
            float scl = __expf(mrow[r] - mn);
            float p0 = __expf(s0 - mn), p1 = __expf(s1 - mn);
            float p2 = __expf(s2 - mn), p3 = __expf(s3 - mn);
            float rs = p0 + p1 + p2 + p3;
            rs += __shfl_xor(rs, 1); rs += __shfl_xor(rs, 2);
            rs += __shfl_xor(rs, 4); rs += __shfl_xor(rs, 8);
            lrow[r] = lrow[r] * scl + rs;
            mrow[r] = mn;
            #pragma unroll
            for (int ni = 0; ni < 4; ++ni) acc[ni][r] *= scl;
            int prow = lg * 4 + r;
            Ps[w][prow][0 * 16 + lr] = f2b(p0);
            Ps[w][prow][1 * 16 + lr] = f2b(p1);
            Ps[w][prow][2 * 16 + lr] = f2b(p2);
            Ps[w][prow][3 * 16 + lr] = f2b(p3);
        }
        __syncthreads();   // P visible; Vs still valid

        // PV: A-frag = P[row lr][key], B-frag = V[key][d] read from Vs[d][key]
        #pragma unroll
        for (int ks = 0; ks < 2; ++ks) {
            bf16x8 pf = *(bf16x8*)&Ps[w][lr][ks * 32 + lg * 8];
            #pragma unroll
            for (int ni = 0; ni < 4; ++ni) {
                bf16x8 vf = *(bf16x8*)&Vs[ni * 16 + lr][ks * 32 + lg * 8];
                acc[ni] = __builtin_amdgcn_mfma_f32_16x16x32_bf16(pf, vf, acc[ni], 0, 0, 0);
            }
        }
        __syncthreads();   // all PV reads done before restaging
    }

    #pragma unroll
    for (int ni = 0; ni < 4; ++ni) {
        #pragma unroll
        for (int r = 0; r < 4; ++r) {
            int t = t0 + lg * 4 + r;
            AO[((size_t)b * NTOK + t) * INNER + h * HD + ni * 16 + lr] =
                f2b(acc[ni][r] / lrow[r]);
        }
    }
}

// ---------------------------------------------------------------------------
extern "C" void kernel_launch(void* const* d_in, const int* in_sizes, int n_in,
                              void* d_out, int out_size, void* d_ws, size_t ws_size,
                              hipStream_t stream) {
    const float* x       = (const float*)d_in[0];
    const float* context = (const float*)d_in[1];
    const float* gamma   = (const float*)d_in[2];
    const float* beta    = (const float*)d_in[3];
    const float* Wq      = (const float*)d_in[4];
    const float* Wk      = (const float*)d_in[5];
    const float* Wv      = (const float*)d_in[6];
    const float* Wo      = (const float*)d_in[7];
    const float* bo      = (const float*)d_in[8];
    float* out = (float*)d_out;

    char* p = (char*)d_ws;
    float* stats = (float*)p;            p += 1024;
    bf16_t* xn   = (bf16_t*)p;           p += (size_t)B * NTOK * C * 2;      // 8 MB
    bf16_t* ctxb = (bf16_t*)p;           p += (size_t)B * CTX * CDIM * 2;    // 3 MB
    bf16_t* Wqt  = (bf16_t*)p;           p += (size_t)INNER * C * 2;
    bf16_t* Wkvt = (bf16_t*)p;           p += (size_t)2 * INNER * CDIM * 2;
    bf16_t* Wot  = (bf16_t*)p;           p += (size_t)C * INNER * 2;
    bf16_t* qb   = (bf16_t*)p;           p += (size_t)B * NH * NTOK * HD * 2;
    bf16_t* kb   = (bf16_t*)p;           p += (size_t)B * NH * CTX * HD * 2;
    bf16_t* vb   = (bf16_t*)p;           p += (size_t)B * NH * CTX * HD * 2;
    bf16_t* ao   = (bf16_t*)p;           p += (size_t)B * NTOK * INNER * 2;

    hipLaunchKernelGGL(gn_stats_kernel, dim3(B * GROUPS), dim3(256), 0, stream, x, stats);
    hipLaunchKernelGGL(gn_apply_kernel, dim3(NTOK / 32, C / 32, B), dim3(256), 0, stream,
                       x, stats, gamma, beta, xn);
    hipLaunchKernelGGL(wcast_kernel, dim3(16, 16), dim3(256), 0, stream, Wq, Wqt, C, INNER, C);
    hipLaunchKernelGGL(wcast_kernel, dim3(24, 16), dim3(256), 0, stream, Wk, Wkvt, CDIM, INNER, CDIM);
    hipLaunchKernelGGL(wcast_kernel, dim3(24, 16), dim3(256), 0, stream,
                       Wv, Wkvt + (size_t)INNER * CDIM, CDIM, INNER, CDIM);
    hipLaunchKernelGGL(wcast_kernel, dim3(16, 16), dim3(256), 0, stream, Wo, Wot, INNER, C, INNER);
    hipLaunchKernelGGL(castctx_kernel, dim3(B * CTX * CDIM / 1024), dim3(256), 0, stream,
                       context, ctxb);
    // Q = xn @ Wq   (M=8192, K=512)
    hipLaunchKernelGGL(gemm_qkv_kernel, dim3(64, 4), dim3(256), 0, stream,
                       xn, Wqt, qb, qb, C, 12);
    // K|V = ctx @ [Wk|Wv]  (M=2048, K=768, N=1024)
    hipLaunchKernelGGL(gemm_qkv_kernel, dim3(16, 8), dim3(256), 0, stream,
                       ctxb, Wkvt, kb, vb, CDIM, 10);
    hipLaunchKernelGGL(attn_kernel, dim3(B * NH * (NTOK / 64)), dim3(256), 0, stream,
                       qb, kb, vb, ao);
    hipLaunchKernelGGL(gemm_o_kernel, dim3(64, 4), dim3(256), 0, stream,
                       ao, Wot, bo, x, out);
}

// Round 3
// 244.853 us; speedup vs baseline: 6.1847x; 1.2685x over previous
//
#include <hip/hip_runtime.h>
#include <hip/hip_bf16.h>

#define B 2
#define C 512
#define NTOK 4096          // d*w*hs
#define GROUPS 32
#define CPG 16
#define CTX 1024
#define CDIM 768
#define NH 8
#define HD 64
#define INNER 512
#define EPS 1e-5f

typedef unsigned short bf16_t;
typedef __attribute__((ext_vector_type(8))) short bf16x8;   // 8 bf16 = 4 VGPRs (MFMA A/B frag)
typedef __attribute__((ext_vector_type(4))) float f32x4;    // MFMA C/D frag

__device__ __forceinline__ bf16_t f2b(float f) {
    unsigned u = __float_as_uint(f);
    u += 0x7fffu + ((u >> 16) & 1u);          // RNE
    return (bf16_t)(u >> 16);
}

// ---------------------------------------------------------------------------
// GroupNorm stats, stage 1: 16 blocks per (b,group); each reduces a contiguous
// 4096-float slice with float4 loads -> one float2 partial (sum, sumsq).
__global__ __launch_bounds__(256) void gn_partial_kernel(const float* __restrict__ x,
                                                         float2* __restrict__ partials) {
    int blk = blockIdx.x;                 // 0..1023
    const float* base = x + (size_t)blk * 4096;
    float s = 0.f, ss = 0.f;
    #pragma unroll
    for (int i = 0; i < 4; ++i) {
        float4 v = *(const float4*)&base[(threadIdx.x + i * 256) * 4];
        s += v.x + v.y + v.z + v.w;
        ss += v.x * v.x + v.y * v.y + v.z * v.z + v.w * v.w;
    }
    #pragma unroll
    for (int o = 32; o > 0; o >>= 1) { s += __shfl_xor(s, o); ss += __shfl_xor(ss, o); }
    __shared__ float ls[2][4];
    int wv = threadIdx.x >> 6, ln = threadIdx.x & 63;
    if (ln == 0) { ls[0][wv] = s; ls[1][wv] = ss; }
    __syncthreads();
    if (threadIdx.x == 0) {
        partials[blk] = make_float2(ls[0][0] + ls[0][1] + ls[0][2] + ls[0][3],
                                    ls[1][0] + ls[1][1] + ls[1][2] + ls[1][3]);
    }
}

// Stage 2: one block; thread g reduces its group's 16 contiguous partials.
__global__ __launch_bounds__(64) void gn_finalize_kernel(const float2* __restrict__ partials,
                                                         float* __restrict__ stats) {
    int g = threadIdx.x;                  // 0..63 = b*32+group
    float s = 0.f, ss = 0.f;
    #pragma unroll
    for (int i = 0; i < 16; ++i) {
        float2 p = partials[g * 16 + i];
        s += p.x; ss += p.y;
    }
    float mu = s / (float)(CPG * NTOK);
    float var = ss / (float)(CPG * NTOK) - mu * mu;
    stats[g] = mu;
    stats[64 + g] = rsqrtf(var + EPS);
}

// ---------------------------------------------------------------------------
// Apply GroupNorm + transpose to bf16 xn[b][t][c].
__global__ __launch_bounds__(256) void gn_apply_kernel(const float* __restrict__ x,
                                                       const float* __restrict__ stats,
                                                       const float* __restrict__ gamma,
                                                       const float* __restrict__ beta,
                                                       bf16_t* __restrict__ xn) {
    __shared__ float tile[32][33];
    int b = blockIdx.z;
    int c0 = blockIdx.y * 32;
    int t0 = blockIdx.x * 32;
    int tt = threadIdx.x & 31, cr = threadIdx.x >> 5;
    #pragma unroll
    for (int i = 0; i < 4; ++i) {
        int c = c0 + cr + 8 * i;
        float mu = stats[b * 32 + (c >> 4)];
        float rs = stats[64 + b * 32 + (c >> 4)];
        float v = x[((size_t)(b * C + c)) * NTOK + t0 + tt];
        tile[cr + 8 * i][tt] = (v - mu) * rs * gamma[c] + beta[c];
    }
    __syncthreads();
    #pragma unroll
    for (int i = 0; i < 4; ++i) {
        int t = t0 + cr + 8 * i;
        int c = c0 + tt;
        xn[((size_t)b * NTOK + t) * C + c] = f2b(tile[tt][cr + 8 * i]);
    }
}

// ---------------------------------------------------------------------------
// Weight transpose+cast: out[n][k] (bf16, row stride ldo) = in[k][n] (fp32).
__global__ __launch_bounds__(256) void wcast_kernel(const float* __restrict__ in,
                                                    bf16_t* __restrict__ out,
                                                    int K, int N, int ldo) {
    __shared__ float t[32][33];
    int k0 = blockIdx.x * 32, n0 = blockIdx.y * 32;
    int xx = threadIdx.x & 31, yy = threadIdx.x >> 5;
    #pragma unroll
    for (int i = 0; i < 4; ++i)
        t[yy + 8 * i][xx] = in[(size_t)(k0 + yy + 8 * i) * N + n0 + xx];
    __syncthreads();
    #pragma unroll
    for (int i = 0; i < 4; ++i)
        out[(size_t)(n0 + yy + 8 * i) * ldo + k0 + xx] = f2b(t[xx][yy + 8 * i]);
}

// context fp32 -> bf16, same layout.
__global__ __launch_bounds__(256) void castctx_kernel(const float* __restrict__ in,
                                                      bf16_t* __restrict__ out) {
    int i = (blockIdx.x * 256 + threadIdx.x) * 4;
    float4 v = *(const float4*)&in[i];
    out[i + 0] = f2b(v.x); out[i + 1] = f2b(v.y);
    out[i + 2] = f2b(v.z); out[i + 3] = f2b(v.w);
}

// ---------------------------------------------------------------------------
// MFMA GEMM, 128x128 tile, 4 waves (2x2), BK=32. C = A[M][K] @ Bt[N][K]^T.
// Epilogue scatters bf16 to head-major [bidx][h][seq][d]; cols >= 512 go to outV.
__global__ __launch_bounds__(256) void gemm_qkv_kernel(
    const bf16_t* __restrict__ A, const bf16_t* __restrict__ Bt,
    bf16_t* __restrict__ outK, bf16_t* __restrict__ outV,
    int K, int seqshift) {
    __shared__ __align__(16) bf16_t As[128][40];   // 40-short rows: 80B, 16B-aligned frag reads
    __shared__ __align__(16) bf16_t Bs[128][40];
    const int tid = threadIdx.x;
    const int l = tid & 63, w = tid >> 6;
    const int wr = w >> 1, wc = w & 1;
    const int lg = l >> 4, lr = l & 15;
    const int m0 = blockIdx.x * 128, n0 = blockIdx.y * 128;
    const int rowA = tid >> 2, c8 = (tid & 3) * 8;
    const int rowB = rowA + 64;
    f32x4 acc[4][4] = {};
    for (int k0 = 0; k0 < K; k0 += 32) {
        *(float4*)&As[rowA][c8] = *(const float4*)&A[(size_t)(m0 + rowA) * K + k0 + c8];
        *(float4*)&As[rowB][c8] = *(const float4*)&A[(size_t)(m0 + rowB) * K + k0 + c8];
        *(float4*)&Bs[rowA][c8] = *(const float4*)&Bt[(size_t)(n0 + rowA) * K + k0 + c8];
        *(float4*)&Bs[rowB][c8] = *(const float4*)&Bt[(size_t)(n0 + rowB) * K + k0 + c8];
        __syncthreads();
        bf16x8 af[4], bfr[4];
        #pragma unroll
        for (int mi = 0; mi < 4; ++mi) af[mi] = *(bf16x8*)&As[wr * 64 + mi * 16 + lr][lg * 8];
        #pragma unroll
        for (int ni = 0; ni < 4; ++ni) bfr[ni] = *(bf16x8*)&Bs[wc * 64 + ni * 16 + lr][lg * 8];
        #pragma unroll
        for (int mi = 0; mi < 4; ++mi)
            #pragma unroll
            for (int ni = 0; ni < 4; ++ni)
                acc[mi][ni] = __builtin_amdgcn_mfma_f32_16x16x32_bf16(af[mi], bfr[ni], acc[mi][ni], 0, 0, 0);
        __syncthreads();
    }
    const int seqmask = (1 << seqshift) - 1;
    #pragma unroll
    for (int ni = 0; ni < 4; ++ni) {
        int n = n0 + wc * 64 + ni * 16 + lr;
        bf16_t* dst = (n < INNER) ? outK : outV;
        int nn = n & (INNER - 1);
        int h = nn >> 6, dd = nn & 63;
        #pragma unroll
        for (int mi = 0; mi < 4; ++mi) {
            #pragma unroll
            for (int r = 0; r < 4; ++r) {
                int m = m0 + wr * 64 + mi * 16 + lg * 4 + r;
                int bidx = m >> seqshift, seq = m & seqmask;
                size_t o = ((((size_t)(bidx * NH + h)) << seqshift) + seq) * HD + dd;
                dst[o] = f2b(acc[mi][ni][r]);
            }
        }
    }
}

// O-projection GEMM (K=512) + bias + residual + transpose to fp32 out[b][c][t].
__global__ __launch_bounds__(256) void gemm_o_kernel(
    const bf16_t* __restrict__ A, const bf16_t* __restrict__ Bt,
    const float* __restrict__ bo, const float* __restrict__ x,
    float* __restrict__ out) {
    __shared__ __align__(16) bf16_t As[128][40];
    __shared__ __align__(16) bf16_t Bs[128][40];
    const int tid = threadIdx.x;
    const int l = tid & 63, w = tid >> 6;
    const int wr = w >> 1, wc = w & 1;
    const int lg = l >> 4, lr = l & 15;
    const int m0 = blockIdx.x * 128, n0 = blockIdx.y * 128;
    const int rowA = tid >> 2, c8 = (tid & 3) * 8;
    const int rowB = rowA + 64;
    f32x4 acc[4][4] = {};
    for (int k0 = 0; k0 < INNER; k0 += 32) {
        *(float4*)&As[rowA][c8] = *(const float4*)&A[(size_t)(m0 + rowA) * INNER + k0 + c8];
        *(float4*)&As[rowB][c8] = *(const float4*)&A[(size_t)(m0 + rowB) * INNER + k0 + c8];
        *(float4*)&Bs[rowA][c8] = *(const float4*)&Bt[(size_t)(n0 + rowA) * INNER + k0 + c8];
        *(float4*)&Bs[rowB][c8] = *(const float4*)&Bt[(size_t)(n0 + rowB) * INNER + k0 + c8];
        __syncthreads();
        bf16x8 af[4], bfr[4];
        #pragma unroll
        for (int mi = 0; mi < 4; ++mi) af[mi] = *(bf16x8*)&As[wr * 64 + mi * 16 + lr][lg * 8];
        #pragma unroll
        for (int ni = 0; ni < 4; ++ni) bfr[ni] = *(bf16x8*)&Bs[wc * 64 + ni * 16 + lr][lg * 8];
        #pragma unroll
        for (int mi = 0; mi < 4; ++mi)
            #pragma unroll
            for (int ni = 0; ni < 4; ++ni)
                acc[mi][ni] = __builtin_amdgcn_mfma_f32_16x16x32_bf16(af[mi], bfr[ni], acc[mi][ni], 0, 0, 0);
        __syncthreads();
    }
    #pragma unroll
    for (int mi = 0; mi < 4; ++mi) {
        int mbase = m0 + wr * 64 + mi * 16 + lg * 4;     // 4 consecutive t (regs r=0..3)
        int t = mbase & (NTOK - 1);
        int bb = mbase >> 12;
        #pragma unroll
        for (int ni = 0; ni < 4; ++ni) {
            int cc = n0 + wc * 64 + ni * 16 + lr;
            size_t o = (((size_t)(bb * C + cc)) << 12) + t;
            float4 xr = *(const float4*)&x[o];
            float bias = bo[cc];
            float4 ov;
            ov.x = acc[mi][ni][0] + bias + xr.x;
            ov.y = acc[mi][ni][1] + bias + xr.y;
            ov.z = acc[mi][ni][2] + bias + xr.z;
            ov.w = acc[mi][ni][3] + bias + xr.w;
            *(float4*)&out[o] = ov;
        }
    }
}

// ---------------------------------------------------------------------------
// Flash attention. Block = 4 waves; wave owns 16 Q rows; KV chunks of 64 in LDS.
__global__ __launch_bounds__(256) void attn_kernel(
    const bf16_t* __restrict__ Q, const bf16_t* __restrict__ Kb,
    const bf16_t* __restrict__ Vb, bf16_t* __restrict__ AO) {
    __shared__ __align__(16) bf16_t Ks[64][72];     // [key][d], 144B rows
    __shared__ __align__(16) bf16_t Vs[64][72];     // [d][key] (transposed at stage time)
    __shared__ __align__(16) bf16_t Ps[4][16][72];  // per-wave P tile [row][key]
    const int tid = threadIdx.x;
    const int l = tid & 63, w = tid >> 6;
    const int lg = l >> 4, lr = l & 15;
    const int bh = blockIdx.x >> 6;                 // b*8+h
    const int tile = blockIdx.x & 63;
    const int b = bh >> 3, h = bh & 7;
    const int t0 = tile * 64 + w * 16;

    // Q fragments, reused across all chunks: A-frag row lr, k = ks*32 + lg*8 + j
    const bf16_t* qbase = Q + ((size_t)bh * NTOK + t0 + lr) * HD;
    bf16x8 qf[2];
    qf[0] = *(const bf16x8*)&qbase[lg * 8];
    qf[1] = *(const bf16x8*)&qbase[32 + lg * 8];

    f32x4 acc[4] = {};                              // O cols d = ni*16+lr, rows 4*lg+r
    float mrow[4], lrow[4];
    #pragma unroll
    for (int r = 0; r < 4; ++r) { mrow[r] = -1e30f; lrow[r] = 0.f; }

    const bf16_t* kbase = Kb + (size_t)bh * CTX * HD;
    const bf16_t* vbase = Vb + (size_t)bh * CTX * HD;
    const int srow = tid >> 3, sc8 = (tid & 7) * 8; // staging coords (2 iters: +32 rows)

    for (int key0 = 0; key0 < CTX; key0 += 64) {
        #pragma unroll
        for (int i = 0; i < 2; ++i) {
            int row = srow + i * 32;
            *(float4*)&Ks[row][sc8] = *(const float4*)&kbase[(size_t)(key0 + row) * HD + sc8];
            float4 vv = *(const float4*)&vbase[(size_t)(key0 + row) * HD + sc8];
            const bf16_t* vsp = (const bf16_t*)&vv;
            #pragma unroll
            for (int j = 0; j < 8; ++j) Vs[sc8 + j][row] = vsp[j];  // transpose scatter
        }
        __syncthreads();

        // QK^T: S[16 q-rows][64 keys], B-frag = K^T read from Ks[key][d]
        f32x4 sf[4] = {};
        #pragma unroll
        for (int ni = 0; ni < 4; ++ni) {
            #pragma unroll
            for (int ks = 0; ks < 2; ++ks) {
                bf16x8 kf = *(bf16x8*)&Ks[ni * 16 + lr][ks * 32 + lg * 8];
                sf[ni] = __builtin_amdgcn_mfma_f32_16x16x32_bf16(qf[ks], kf, sf[ni], 0, 0, 0);
            }
        }

        // Online softmax; thread holds rows 4*lg+r, cols ni*16+lr.
        #pragma unroll
        for (int r = 0; r < 4; ++r) {
            float s0 = sf[0][r] * 0.125f, s1 = sf[1][r] * 0.125f;
            float s2 = sf[2][r] * 0.125f, s3 = sf[3][r] * 0.125f;
            float cm = fmaxf(fmaxf(s0, s1), fmaxf(s2, s3));
            cm = fmaxf(cm, __shfl_xor(cm, 1));
            cm = fmaxf(cm, __shfl_xor(cm, 2));
            cm = fmaxf(cm, __shfl_xor(cm, 4));
            cm = fmaxf(cm, __shfl_xor(cm, 8));
            float mn = fmaxf(mrow[r], cm);
            float scl = __expf(mrow[r] - mn);
            float p0 = __expf(s0 - mn), p1 = __expf(s1 - mn);
            float p2 = __expf(s2 - mn), p3 = __expf(s3 - mn);
            float rs = p0 + p1 + p2 + p3;
            rs += __shfl_xor(rs, 1); rs += __shfl_xor(rs, 2);
            rs += __shfl_xor(rs, 4); rs += __shfl_xor(rs, 8);
            lrow[r] = lrow[r] * scl + rs;
            mrow[r] = mn;
            #pragma unroll
            for (int ni = 0; ni < 4; ++ni) acc[ni][r] *= scl;
            int prow = lg * 4 + r;
            Ps[w][prow][0 * 16 + lr] = f2b(p0);
            Ps[w][prow][1 * 16 + lr] = f2b(p1);
            Ps[w][prow][2 * 16 + lr] = f2b(p2);
            Ps[w][prow][3 * 16 + lr] = f2b(p3);
        }
        __syncthreads();   // P visible; Vs still valid

        // PV: A-frag = P[row lr][key], B-frag = V[key][d] read from Vs[d][key]
        #pragma unroll
        for (int ks = 0; ks < 2; ++ks) {
            bf16x8 pf = *(bf16x8*)&Ps[w][lr][ks * 32 + lg * 8];
            #pragma unroll
            for (int ni = 0; ni < 4; ++ni) {
                bf16x8 vf = *(bf16x8*)&Vs[ni * 16 + lr][ks * 32 + lg * 8];
                acc[ni] = __builtin_amdgcn_mfma_f32_16x16x32_bf16(pf, vf, acc[ni], 0, 0, 0);
            }
        }
        __syncthreads();   // all PV reads done before restaging
    }

    #pragma unroll
    for (int ni = 0; ni < 4; ++ni) {
        #pragma unroll
        for (int r = 0; r < 4; ++r) {
            int t = t0 + lg * 4 + r;
            AO[((size_t)b * NTOK + t) * INNER + h * HD + ni * 16 + lr] =
                f2b(acc[ni][r] / lrow[r]);
        }
    }
}

// ---------------------------------------------------------------------------
extern "C" void kernel_launch(void* const* d_in, const int* in_sizes, int n_in,
                              void* d_out, int out_size, void* d_ws, size_t ws_size,
                              hipStream_t stream) {
    const float* x       = (const float*)d_in[0];
    const float* context = (const float*)d_in[1];
    const float* gamma   = (const float*)d_in[2];
    const float* beta    = (const float*)d_in[3];
    const float* Wq      = (const float*)d_in[4];
    const float* Wk      = (const float*)d_in[5];
    const float* Wv      = (const float*)d_in[6];
    const float* Wo      = (const float*)d_in[7];
    const float* bo      = (const float*)d_in[8];
    float* out = (float*)d_out;

    char* p = (char*)d_ws;
    float* stats = (float*)p;            p += 1024;
    float2* parts = (float2*)p;          p += 1024 * sizeof(float2);
    bf16_t* xn   = (bf16_t*)p;           p += (size_t)B * NTOK * C * 2;      // 8 MB
    bf16_t* ctxb = (bf16_t*)p;           p += (size_t)B * CTX * CDIM * 2;    // 3 MB
    bf16_t* Wqt  = (bf16_t*)p;           p += (size_t)INNER * C * 2;
    bf16_t* Wkvt = (bf16_t*)p;           p += (size_t)2 * INNER * CDIM * 2;
    bf16_t* Wot  = (bf16_t*)p;           p += (size_t)C * INNER * 2;
    bf16_t* qb   = (bf16_t*)p;           p += (size_t)B * NH * NTOK * HD * 2;
    bf16_t* kb   = (bf16_t*)p;           p += (size_t)B * NH * CTX * HD * 2;
    bf16_t* vb   = (bf16_t*)p;           p += (size_t)B * NH * CTX * HD * 2;
    bf16_t* ao   = (bf16_t*)p;           p += (size_t)B * NTOK * INNER * 2;

    hipLaunchKernelGGL(gn_partial_kernel, dim3(1024), dim3(256), 0, stream, x, parts);
    hipLaunchKernelGGL(gn_finalize_kernel, dim3(1), dim3(64), 0, stream, parts, stats);
    hipLaunchKernelGGL(gn_apply_kernel, dim3(NTOK / 32, C / 32, B), dim3(256), 0, stream,
                       x, stats, gamma, beta, xn);
    hipLaunchKernelGGL(wcast_kernel, dim3(16, 16), dim3(256), 0, stream, Wq, Wqt, C, INNER, C);
    hipLaunchKernelGGL(wcast_kernel, dim3(24, 16), dim3(256), 0, stream, Wk, Wkvt, CDIM, INNER, CDIM);
    hipLaunchKernelGGL(wcast_kernel, dim3(24, 16), dim3(256), 0, stream,
                       Wv, Wkvt + (size_t)INNER * CDIM, CDIM, INNER, CDIM);
    hipLaunchKernelGGL(wcast_kernel, dim3(16, 16), dim3(256), 0, stream, Wo, Wot, INNER, C, INNER);
    hipLaunchKernelGGL(castctx_kernel, dim3(B * CTX * CDIM / 1024), dim3(256), 0, stream,
                       context, ctxb);
    // Q = xn @ Wq   (M=8192, K=512)
    hipLaunchKernelGGL(gemm_qkv_kernel, dim3(64, 4), dim3(256), 0, stream,
                       xn, Wqt, qb, qb, C, 12);
    // K|V = ctx @ [Wk|Wv]  (M=2048, K=768, N=1024)
    hipLaunchKernelGGL(gemm_qkv_kernel, dim3(16, 8), dim3(256), 0, stream,
                       ctxb, Wkvt, kb, vb, CDIM, 10);
    hipLaunchKernelGGL(attn_kernel, dim3(B * NH * (NTOK / 64)), dim3(256), 0, stream,
                       qb, kb, vb, ao);
    hipLaunchKernelGGL(gemm_o_kernel, dim3(64, 4), dim3(256), 0, stream,
                       ao, Wot, bo, x, out);
}

// Round 5
// 201.825 us; speedup vs baseline: 7.5032x; 1.2132x over previous
//
#include <hip/hip_runtime.h>
#include <hip/hip_bf16.h>

#define B 2
#define C 512
#define NTOK 4096          // d*w*hs
#define GROUPS 32
#define CPG 16
#define CTX 1024
#define CDIM 768
#define NH 8
#define HD 64
#define INNER 512
#define EPS 1e-5f
#define KVBLK 64
#define NCH (CTX / KVBLK)  // 16

typedef unsigned short bf16_t;
typedef __attribute__((ext_vector_type(8))) short bf16x8;   // 8 bf16 = 4 VGPRs (MFMA A/B frag)
typedef __attribute__((ext_vector_type(4))) float f32x4;    // MFMA C/D frag

__device__ __forceinline__ bf16_t f2b(float f) {
    unsigned u = __float_as_uint(f);
    u += 0x7fffu + ((u >> 16) & 1u);          // RNE
    return (bf16_t)(u >> 16);
}

// XOR-swizzle for 64-col bf16 LDS tiles (row stride 128 B): spreads the
// 16-B slot of each row across 8 slots -> conflict-free b128 col-reads.
__device__ __forceinline__ int swz(int row, int col) {
    return row * 64 + (col ^ ((row & 7) << 3));
}

// ---------------------------------------------------------------------------
// GroupNorm stats, stage 1: 1024 blocks, each reduces a contiguous 4096-float
// slice with float4 loads -> one float2 partial (sum, sumsq).
__global__ __launch_bounds__(256) void gn_partial_kernel(const float* __restrict__ x,
                                                         float2* __restrict__ partials) {
    int blk = blockIdx.x;                 // 0..1023
    const float* base = x + (size_t)blk * 4096;
    float s = 0.f, ss = 0.f;
    #pragma unroll
    for (int i = 0; i < 4; ++i) {
        float4 v = *(const float4*)&base[(threadIdx.x + i * 256) * 4];
        s += v.x + v.y + v.z + v.w;
        ss += v.x * v.x + v.y * v.y + v.z * v.z + v.w * v.w;
    }
    #pragma unroll
    for (int o = 32; o > 0; o >>= 1) { s += __shfl_xor(s, o); ss += __shfl_xor(ss, o); }
    __shared__ float ls[2][4];
    int wv = threadIdx.x >> 6, ln = threadIdx.x & 63;
    if (ln == 0) { ls[0][wv] = s; ls[1][wv] = ss; }
    __syncthreads();
    if (threadIdx.x == 0) {
        partials[blk] = make_float2(ls[0][0] + ls[0][1] + ls[0][2] + ls[0][3],
                                    ls[1][0] + ls[1][1] + ls[1][2] + ls[1][3]);
    }
}

// Stage 2: one block; thread g reduces its group's 16 contiguous partials.
__global__ __launch_bounds__(64) void gn_finalize_kernel(const float2* __restrict__ partials,
                                                         float* __restrict__ stats) {
    int g = threadIdx.x;                  // 0..63 = b*32+group
    float s = 0.f, ss = 0.f;
    #pragma unroll
    for (int i = 0; i < 16; ++i) {
        float2 p = partials[g * 16 + i];
        s += p.x; ss += p.y;
    }
    float mu = s / (float)(CPG * NTOK);
    float var = ss / (float)(CPG * NTOK) - mu * mu;
    stats[g] = mu;
    stats[64 + g] = rsqrtf(var + EPS);
}

// ---------------------------------------------------------------------------
// Apply GroupNorm + transpose to bf16 xn[b][t][c].
__global__ __launch_bounds__(256) void gn_apply_kernel(const float* __restrict__ x,
                                                       const float* __restrict__ stats,
                                                       const float* __restrict__ gamma,
                                                       const float* __restrict__ beta,
                                                       bf16_t* __restrict__ xn) {
    __shared__ float tile[32][33];
    int b = blockIdx.z;
    int c0 = blockIdx.y * 32;
    int t0 = blockIdx.x * 32;
    int tt = threadIdx.x & 31, cr = threadIdx.x >> 5;
    #pragma unroll
    for (int i = 0; i < 4; ++i) {
        int c = c0 + cr + 8 * i;
        float mu = stats[b * 32 + (c >> 4)];
        float rs = stats[64 + b * 32 + (c >> 4)];
        float v = x[((size_t)(b * C + c)) * NTOK + t0 + tt];
        tile[cr + 8 * i][tt] = (v - mu) * rs * gamma[c] + beta[c];
    }
    __syncthreads();
    #pragma unroll
    for (int i = 0; i < 4; ++i) {
        int t = t0 + cr + 8 * i;
        int c = c0 + tt;
        xn[((size_t)b * NTOK + t) * C + c] = f2b(tile[tt][cr + 8 * i]);
    }
}

// ---------------------------------------------------------------------------
// Weight transpose+cast: out[n][k] (bf16, row stride ldo) = in[k][n] (fp32).
__global__ __launch_bounds__(256) void wcast_kernel(const float* __restrict__ in,
                                                    bf16_t* __restrict__ out,
                                                    int K, int N, int ldo) {
    __shared__ float t[32][33];
    int k0 = blockIdx.x * 32, n0 = blockIdx.y * 32;
    int xx = threadIdx.x & 31, yy = threadIdx.x >> 5;
    #pragma unroll
    for (int i = 0; i < 4; ++i)
        t[yy + 8 * i][xx] = in[(size_t)(k0 + yy + 8 * i) * N + n0 + xx];
    __syncthreads();
    #pragma unroll
    for (int i = 0; i < 4; ++i)
        out[(size_t)(n0 + yy + 8 * i) * ldo + k0 + xx] = f2b(t[xx][yy + 8 * i]);
}

// context fp32 -> bf16, same layout.
__global__ __launch_bounds__(256) void castctx_kernel(const float* __restrict__ in,
                                                      bf16_t* __restrict__ out) {
    int i = (blockIdx.x * 256 + threadIdx.x) * 4;
    float4 v = *(const float4*)&in[i];
    out[i + 0] = f2b(v.x); out[i + 1] = f2b(v.y);
    out[i + 2] = f2b(v.z); out[i + 3] = f2b(v.w);
}

// ---------------------------------------------------------------------------
// MFMA GEMM, 64x64 tile, 4 waves (2x2), BK=32, reg-prefetch 2-phase loop.
// C = A[M][K] @ Bt[N][K]^T. Epilogue scatters bf16*oscale to head-major
// [bidx][h][seq][d]; cols >= 512 go to outV ([bidx][h][d][seq] when vtrans).
__global__ __launch_bounds__(256) void gemm_qkv_kernel(
    const bf16_t* __restrict__ A, const bf16_t* __restrict__ Bt,
    bf16_t* __restrict__ outK, bf16_t* __restrict__ outV,
    int K, int seqshift, float oscale, int vtrans) {
    __shared__ __align__(16) bf16_t As[64][40];
    __shared__ __align__(16) bf16_t Bs[64][40];
    const int tid = threadIdx.x;
    const int l = tid & 63, w = tid >> 6;
    const int wr = w >> 1, wc = w & 1;
    const int lg = l >> 4, lr = l & 15;
    const int m0 = blockIdx.x * 64, n0 = blockIdx.y * 64;
    const int rowS = tid >> 2, c8 = (tid & 3) * 8;
    const bf16_t* pa = A  + (size_t)(m0 + rowS) * K + c8;
    const bf16_t* pb = Bt + (size_t)(n0 + rowS) * K + c8;
    f32x4 acc[2][2] = {};
    float4 ra = *(const float4*)pa;
    float4 rb = *(const float4*)pb;
    *(float4*)&As[rowS][c8] = ra;
    *(float4*)&Bs[rowS][c8] = rb;
    for (int k0 = 0; k0 < K; k0 += 32) {
        __syncthreads();
        if (k0 + 32 < K) {                          // prefetch next K-step
            ra = *(const float4*)(pa + k0 + 32);
            rb = *(const float4*)(pb + k0 + 32);
        }
        bf16x8 af[2], bfm[2];
        af[0]  = *(bf16x8*)&As[wr * 32 + lr][lg * 8];
        af[1]  = *(bf16x8*)&As[wr * 32 + 16 + lr][lg * 8];
        bfm[0] = *(bf16x8*)&Bs[wc * 32 + lr][lg * 8];
        bfm[1] = *(bf16x8*)&Bs[wc * 32 + 16 + lr][lg * 8];
        #pragma unroll
        for (int mi = 0; mi < 2; ++mi)
            #pragma unroll
            for (int ni = 0; ni < 2; ++ni)
                acc[mi][ni] = __builtin_amdgcn_mfma_f32_16x16x32_bf16(af[mi], bfm[ni], acc[mi][ni], 0, 0, 0);
        __syncthreads();
        if (k0 + 32 < K) {
            *(float4*)&As[rowS][c8] = ra;
            *(float4*)&Bs[rowS][c8] = rb;
        }
    }
    const int seqmask = (1 << seqshift) - 1;
    #pragma unroll
    for (int ni = 0; ni < 2; ++ni) {
        int n = n0 + wc * 32 + ni * 16 + lr;
        int nn = n & (INNER - 1);
        int h = nn >> 6, dd = nn & 63;
        bool isV = (n >= INNER);
        #pragma unroll
        for (int mi = 0; mi < 2; ++mi) {
            int mb = m0 + wr * 32 + mi * 16 + lg * 4;
            int bidx = mb >> seqshift, seqb = mb & seqmask;
            if (isV && vtrans) {
                ushort4 pv;                          // 4 consecutive seq packed
                pv.x = f2b(acc[mi][ni][0] * oscale);
                pv.y = f2b(acc[mi][ni][1] * oscale);
                pv.z = f2b(acc[mi][ni][2] * oscale);
                pv.w = f2b(acc[mi][ni][3] * oscale);
                *(ushort4*)&outV[((size_t)(bidx * NH + h) * HD + dd) * (size_t)(seqmask + 1) + seqb] = pv;
            } else {
                bf16_t* dst = isV ? outV : outK;
                #pragma unroll
                for (int r = 0; r < 4; ++r)
                    dst[(((size_t)(bidx * NH + h) << seqshift) + seqb + r) * HD + dd] =
                        f2b(acc[mi][ni][r] * oscale);
            }
        }
    }
}

// O-projection GEMM (K=512), 64x64 tile + prefetch; epilogue bias + residual
// + transpose to fp32 out[b][c][t] with float4 stores.
__global__ __launch_bounds__(256) void gemm_o_kernel(
    const bf16_t* __restrict__ A, const bf16_t* __restrict__ Bt,
    const float* __restrict__ bo, const float* __restrict__ x,
    float* __restrict__ out) {
    __shared__ __align__(16) bf16_t As[64][40];
    __shared__ __align__(16) bf16_t Bs[64][40];
    const int tid = threadIdx.x;
    const int l = tid & 63, w = tid >> 6;
    const int wr = w >> 1, wc = w & 1;
    const int lg = l >> 4, lr = l & 15;
    const int m0 = blockIdx.x * 64, n0 = blockIdx.y * 64;
    const int rowS = tid >> 2, c8 = (tid & 3) * 8;
    const bf16_t* pa = A  + (size_t)(m0 + rowS) * INNER + c8;
    const bf16_t* pb = Bt + (size_t)(n0 + rowS) * INNER + c8;
    f32x4 acc[2][2] = {};
    float4 ra = *(const float4*)pa;
    float4 rb = *(const float4*)pb;
    *(float4*)&As[rowS][c8] = ra;
    *(float4*)&Bs[rowS][c8] = rb;
    for (int k0 = 0; k0 < INNER; k0 += 32) {
        __syncthreads();
        if (k0 + 32 < INNER) {
            ra = *(const float4*)(pa + k0 + 32);
            rb = *(const float4*)(pb + k0 + 32);
        }
        bf16x8 af[2], bfm[2];
        af[0]  = *(bf16x8*)&As[wr * 32 + lr][lg * 8];
        af[1]  = *(bf16x8*)&As[wr * 32 + 16 + lr][lg * 8];
        bfm[0] = *(bf16x8*)&Bs[wc * 32 + lr][lg * 8];
        bfm[1] = *(bf16x8*)&Bs[wc * 32 + 16 + lr][lg * 8];
        #pragma unroll
        for (int mi = 0; mi < 2; ++mi)
            #pragma unroll
            for (int ni = 0; ni < 2; ++ni)
                acc[mi][ni] = __builtin_amdgcn_mfma_f32_16x16x32_bf16(af[mi], bfm[ni], acc[mi][ni], 0, 0, 0);
        __syncthreads();
        if (k0 + 32 < INNER) {
            *(float4*)&As[rowS][c8] = ra;
            *(float4*)&Bs[rowS][c8] = rb;
        }
    }
    #pragma unroll
    for (int mi = 0; mi < 2; ++mi) {
        int mb = m0 + wr * 32 + mi * 16 + lg * 4;   // 4 consecutive t
        int t = mb & (NTOK - 1);
        int bb = mb >> 12;
        #pragma unroll
        for (int ni = 0; ni < 2; ++ni) {
            int cc = n0 + wc * 32 + ni * 16 + lr;
            size_t o = (((size_t)(bb * C + cc)) << 12) + t;
            float4 xr = *(const float4*)&x[o];
            float bias = bo[cc];
            float4 ov;
            ov.x = acc[mi][ni][0] + bias + xr.x;
            ov.y = acc[mi][ni][1] + bias + xr.y;
            ov.z = acc[mi][ni][2] + bias + xr.z;
            ov.w = acc[mi][ni][3] + bias + xr.w;
            *(float4*)&out[o] = ov;
        }
    }
}

// ---------------------------------------------------------------------------
// Flash attention. 4 waves x 32 q-rows; K [bh][key][d], V pre-transposed
// [bh][d][key]. Swizzled LDS, reg-prefetched chunks, 2 barriers/chunk.
// Q comes pre-scaled by HD^-0.5 (folded into Q-projection).
__global__ __launch_bounds__(256) void attn_kernel(
    const bf16_t* __restrict__ Q, const bf16_t* __restrict__ Kb,
    const bf16_t* __restrict__ Vt, bf16_t* __restrict__ AO) {
    __shared__ __align__(16) bf16_t Ks[64 * 64];    // [key][d] swizzled, 8 KB
    __shared__ __align__(16) bf16_t Vs[64 * 64];    // [d][key] swizzled, 8 KB
    __shared__ __align__(16) bf16_t Ps[4][32 * 64]; // per-wave P [qrow][key], 16 KB
    const int tid = threadIdx.x;
    const int l = tid & 63, w = tid >> 6;
    const int lg = l >> 4, lr = l & 15;
    const int bh = blockIdx.x >> 5;                 // b*8+h
    const int tile = blockIdx.x & 31;
    const int b = bh >> 3, h = bh & 7;
    const int t0 = tile * 128 + w * 32;

    bf16x8 qf[2][2];                                // [mi][ks]
    #pragma unroll
    for (int mi = 0; mi < 2; ++mi) {
        const bf16_t* qb = Q + ((size_t)bh * NTOK + t0 + mi * 16 + lr) * HD;
        qf[mi][0] = *(const bf16x8*)&qb[lg * 8];
        qf[mi][1] = *(const bf16x8*)&qb[32 + lg * 8];
    }

    f32x4 acc[2][4] = {};
    float mrow[2][4], lrow[2][4];
    #pragma unroll
    for (int mi = 0; mi < 2; ++mi)
        #pragma unroll
        for (int r = 0; r < 4; ++r) { mrow[mi][r] = -1e30f; lrow[mi][r] = 0.f; }

    const bf16_t* kbase = Kb + (size_t)bh * CTX * HD;
    const bf16_t* vbase = Vt + (size_t)bh * HD * CTX;
    const int srow = tid >> 3, sc8 = (tid & 7) * 8;

    float4 kr0 = *(const float4*)&kbase[(size_t)srow * HD + sc8];
    float4 kr1 = *(const float4*)&kbase[(size_t)(srow + 32) * HD + sc8];
    float4 vr0 = *(const float4*)&vbase[(size_t)srow * CTX + sc8];
    float4 vr1 = *(const float4*)&vbase[(size_t)(srow + 32) * CTX + sc8];
    *(float4*)&Ks[swz(srow, sc8)] = kr0;
    *(float4*)&Ks[swz(srow + 32, sc8)] = kr1;
    *(float4*)&Vs[swz(srow, sc8)] = vr0;
    *(float4*)&Vs[swz(srow + 32, sc8)] = vr1;

    for (int c = 0; c < NCH; ++c) {
        __syncthreads();                            // chunk c staged
        if (c + 1 < NCH) {                          // prefetch chunk c+1 to regs
            int k1 = (c + 1) * KVBLK;
            kr0 = *(const float4*)&kbase[(size_t)(k1 + srow) * HD + sc8];
            kr1 = *(const float4*)&kbase[(size_t)(k1 + srow + 32) * HD + sc8];
            vr0 = *(const float4*)&vbase[(size_t)srow * CTX + k1 + sc8];
            vr1 = *(const float4*)&vbase[(size_t)(srow + 32) * CTX + k1 + sc8];
        }
        // QK^T: S[32 q-rows][64 keys]
        f32x4 sf[2][4] = {};
        #pragma unroll
        for (int ks = 0; ks < 2; ++ks)
            #pragma unroll
            for (int ni = 0; ni < 4; ++ni) {
                bf16x8 kf = *(bf16x8*)&Ks[swz(ni * 16 + lr, ks * 32 + lg * 8)];
                sf[0][ni] = __builtin_amdgcn_mfma_f32_16x16x32_bf16(qf[0][ks], kf, sf[0][ni], 0, 0, 0);
                sf[1][ni] = __builtin_amdgcn_mfma_f32_16x16x32_bf16(qf[1][ks], kf, sf[1][ni], 0, 0, 0);
            }
        // Online softmax (rows 4*lg+r per mi-tile; reduce over 16-lane lr group)
        #pragma unroll
        for (int mi = 0; mi < 2; ++mi)
            #pragma unroll
            for (int r = 0; r < 4; ++r) {
                float s0 = sf[mi][0][r], s1 = sf[mi][1][r];
                float s2 = sf[mi][2][r], s3 = sf[mi][3][r];
                float cm = fmaxf(fmaxf(s0, s1), fmaxf(s2, s3));
                cm = fmaxf(cm, __shfl_xor(cm, 1));
                cm = fmaxf(cm, __shfl_xor(cm, 2));
                cm = fmaxf(cm, __shfl_xor(cm, 4));
                cm = fmaxf(cm, __shfl_xor(cm, 8));
                float mn = fmaxf(mrow[mi][r], cm);
                float scl = __expf(mrow[mi][r] - mn);
                float p0 = __expf(s0 - mn), p1 = __expf(s1 - mn);
                float p2 = __expf(s2 - mn), p3 = __expf(s3 - mn);
                float rs = p0 + p1 + p2 + p3;
                rs += __shfl_xor(rs, 1); rs += __shfl_xor(rs, 2);
                rs += __shfl_xor(rs, 4); rs += __shfl_xor(rs, 8);
                lrow[mi][r] = lrow[mi][r] * scl + rs;
                mrow[mi][r] = mn;
                #pragma unroll
                for (int ni = 0; ni < 4; ++ni) acc[mi][ni][r] *= scl;
                int prow = mi * 16 + lg * 4 + r;
                Ps[w][swz(prow, 0 * 16 + lr)] = f2b(p0);
                Ps[w][swz(prow, 1 * 16 + lr)] = f2b(p1);
                Ps[w][swz(prow, 2 * 16 + lr)] = f2b(p2);
                Ps[w][swz(prow, 3 * 16 + lr)] = f2b(p3);
            }
        // PV (Ps is wave-private: in-wave DS ordering suffices, no barrier)
        #pragma unroll
        for (int ks = 0; ks < 2; ++ks) {
            bf16x8 pf0 = *(bf16x8*)&Ps[w][swz(lr, ks * 32 + lg * 8)];
            bf16x8 pf1 = *(bf16x8*)&Ps[w][swz(16 + lr, ks * 32 + lg * 8)];
            #pragma unroll
            for (int ni = 0; ni < 4; ++ni) {
                bf16x8 vf = *(bf16x8*)&Vs[swz(ni * 16 + lr, ks * 32 + lg * 8)];
                acc[0][ni] = __builtin_amdgcn_mfma_f32_16x16x32_bf16(pf0, vf, acc[0][ni], 0, 0, 0);
                acc[1][ni] = __builtin_amdgcn_mfma_f32_16x16x32_bf16(pf1, vf, acc[1][ni], 0, 0, 0);
            }
        }
        __syncthreads();                            // all reads of chunk c done
        if (c + 1 < NCH) {
            *(float4*)&Ks[swz(srow, sc8)] = kr0;
            *(float4*)&Ks[swz(srow + 32, sc8)] = kr1;
            *(float4*)&Vs[swz(srow, sc8)] = vr0;
            *(float4*)&Vs[swz(srow + 32, sc8)] = vr1;
        }
    }

    #pragma unroll
    for (int mi = 0; mi < 2; ++mi)
        #pragma unroll
        for (int ni = 0; ni < 4; ++ni)
            #pragma unroll
            for (int r = 0; r < 4; ++r) {
                int t = t0 + mi * 16 + lg * 4 + r;
                AO[((size_t)b * NTOK + t) * INNER + h * HD + ni * 16 + lr] =
                    f2b(acc[mi][ni][r] / lrow[mi][r]);
            }
}

// ---------------------------------------------------------------------------
extern "C" void kernel_launch(void* const* d_in, const int* in_sizes, int n_in,
                              void* d_out, int out_size, void* d_ws, size_t ws_size,
                              hipStream_t stream) {
    const float* x       = (const float*)d_in[0];
    const float* context = (const float*)d_in[1];
    const float* gamma   = (const float*)d_in[2];
    const float* beta    = (const float*)d_in[3];
    const float* Wq      = (const float*)d_in[4];
    const float* Wk      = (const float*)d_in[5];
    const float* Wv      = (const float*)d_in[6];
    const float* Wo      = (const float*)d_in[7];
    const float* bo      = (const float*)d_in[8];
    float* out = (float*)d_out;

    char* p = (char*)d_ws;
    float* stats = (float*)p;            p += 1024;
    float2* parts = (float2*)p;          p += 1024 * sizeof(float2);
    bf16_t* xn   = (bf16_t*)p;           p += (size_t)B * NTOK * C * 2;      // 8 MB
    bf16_t* ctxb = (bf16_t*)p;           p += (size_t)B * CTX * CDIM * 2;    // 3 MB
    bf16_t* Wqt  = (bf16_t*)p;           p += (size_t)INNER * C * 2;
    bf16_t* Wkvt = (bf16_t*)p;           p += (size_t)2 * INNER * CDIM * 2;
    bf16_t* Wot  = (bf16_t*)p;           p += (size_t)C * INNER * 2;
    bf16_t* qb   = (bf16_t*)p;           p += (size_t)B * NH * NTOK * HD * 2;
    bf16_t* kb   = (bf16_t*)p;           p += (size_t)B * NH * CTX * HD * 2;
    bf16_t* vb   = (bf16_t*)p;           p += (size_t)B * NH * CTX * HD * 2; // V^T [b,h,d,key]
    bf16_t* ao   = (bf16_t*)p;           p += (size_t)B * NTOK * INNER * 2;

    hipLaunchKernelGGL(gn_partial_kernel, dim3(1024), dim3(256), 0, stream, x, parts);
    hipLaunchKernelGGL(gn_finalize_kernel, dim3(1), dim3(64), 0, stream, parts, stats);
    hipLaunchKernelGGL(gn_apply_kernel, dim3(NTOK / 32, C / 32, B), dim3(256), 0, stream,
                       x, stats, gamma, beta, xn);
    hipLaunchKernelGGL(wcast_kernel, dim3(16, 16), dim3(256), 0, stream, Wq, Wqt, C, INNER, C);
    hipLaunchKernelGGL(wcast_kernel, dim3(24, 16), dim3(256), 0, stream, Wk, Wkvt, CDIM, INNER, CDIM);
    hipLaunchKernelGGL(wcast_kernel, dim3(24, 16), dim3(256), 0, stream,
                       Wv, Wkvt + (size_t)INNER * CDIM, CDIM, INNER, CDIM);
    hipLaunchKernelGGL(wcast_kernel, dim3(16, 16), dim3(256), 0, stream, Wo, Wot, INNER, C, INNER);
    hipLaunchKernelGGL(castctx_kernel, dim3(B * CTX * CDIM / 1024), dim3(256), 0, stream,
                       context, ctxb);
    // Q = xn @ Wq, pre-scaled by HD^-0.5 (M=8192, K=512, N=512)
    hipLaunchKernelGGL(gemm_qkv_kernel, dim3(128, 8), dim3(256), 0, stream,
                       xn, Wqt, qb, qb, C, 12, 0.125f, 0);
    // K|V = ctx @ [Wk|Wv]; V written transposed (M=2048, K=768, N=1024)
    hipLaunchKernelGGL(gemm_qkv_kernel, dim3(32, 16), dim3(256), 0, stream,
                       ctxb, Wkvt, kb, vb, CDIM, 10, 1.0f, 1);
    hipLaunchKernelGGL(attn_kernel, dim3(B * NH * (NTOK / 128)), dim3(256), 0, stream,
                       qb, kb, vb, ao);
    hipLaunchKernelGGL(gemm_o_kernel, dim3(128, 8), dim3(256), 0, stream,
                       ao, Wot, bo, x, out);
}

// Round 7
// 194.715 us; speedup vs baseline: 7.7772x; 1.0365x over previous
//
#include <hip/hip_runtime.h>
#include <hip/hip_bf16.h>

#define B 2
#define C 512
#define NTOK 4096          // d*w*hs
#define GROUPS 32
#define CPG 16
#define CTX 1024
#define CDIM 768
#define NH 8
#define HD 64
#define INNER 512
#define EPS 1e-5f
#define KVBLK 64
#define NCH (CTX / KVBLK)  // 16
#define LOG2E 1.44269504f

typedef unsigned short bf16_t;
typedef __attribute__((ext_vector_type(8))) short bf16x8;   // 8 bf16 = 4 VGPRs (MFMA A/B frag)
typedef __attribute__((ext_vector_type(4))) float f32x4;    // MFMA C/D frag

__device__ __forceinline__ bf16_t f2b(float f) {
    unsigned u = __float_as_uint(f);
    u += 0x7fffu + ((u >> 16) & 1u);          // RNE
    return (bf16_t)(u >> 16);
}

// pack 8 fp32 -> 8 bf16 in a float4-sized container (for 16B LDS stores)
__device__ __forceinline__ float4 pack8(const float* v) {
    union { ushort s[8]; float4 f; } u;
    #pragma unroll
    for (int j = 0; j < 8; ++j) u.s[j] = f2b(v[j]);
    return u.f;
}

// XOR-swizzle for 64-col bf16 LDS tiles (row stride 128 B): spreads the
// 16-B slot of each row across 8 slots -> conflict-free b128 col-reads.
__device__ __forceinline__ int swz(int row, int col) {
    return row * 64 + (col ^ ((row & 7) << 3));
}

// ---------------------------------------------------------------------------
// GroupNorm stats, stage 1: 1024 blocks (= one channel each), float4 loads ->
// one float2 partial (sum, sumsq) per channel.  partials[b*C + c].
__global__ __launch_bounds__(256) void gn_partial_kernel(const float* __restrict__ x,
                                                         float2* __restrict__ partials) {
    int blk = blockIdx.x;                 // 0..B*C-1
    const float* base = x + (size_t)blk * 4096;
    float s = 0.f, ss = 0.f;
    #pragma unroll
    for (int i = 0; i < 4; ++i) {
        float4 v = *(const float4*)&base[(threadIdx.x + i * 256) * 4];
        s += v.x + v.y + v.z + v.w;
        ss += v.x * v.x + v.y * v.y + v.z * v.z + v.w * v.w;
    }
    #pragma unroll
    for (int o = 32; o > 0; o >>= 1) { s += __shfl_xor(s, o); ss += __shfl_xor(ss, o); }
    __shared__ float ls[2][4];
    int wv = threadIdx.x >> 6, ln = threadIdx.x & 63;
    if (ln == 0) { ls[0][wv] = s; ls[1][wv] = ss; }
    __syncthreads();
    if (threadIdx.x == 0) {
        partials[blk] = make_float2(ls[0][0] + ls[0][1] + ls[0][2] + ls[0][3],
                                    ls[1][0] + ls[1][1] + ls[1][2] + ls[1][3]);
    }
}

// ---------------------------------------------------------------------------
// Apply GroupNorm + transpose to bf16 xn[b][t][c].  Finalizes the 2 groups'
// stats it needs from the per-channel partials (gn_finalize fused away).
__global__ __launch_bounds__(256) void gn_apply_kernel(const float* __restrict__ x,
                                                       const float2* __restrict__ partials,
                                                       const float* __restrict__ gamma,
                                                       const float* __restrict__ beta,
                                                       bf16_t* __restrict__ xn) {
    __shared__ float tile[32][33];
    __shared__ float gmu[2], grs[2];
    int b = blockIdx.z;
    int c0 = blockIdx.y * 32;
    int t0 = blockIdx.x * 32;
    int tid = threadIdx.x;
    if (tid < 32) {                        // finalize the 2 groups covering c0..c0+31
        int gi = tid >> 4, pi = tid & 15;
        float2 pp = partials[b * C + c0 + gi * 16 + pi];
        float s = pp.x, ss = pp.y;
        #pragma unroll
        for (int o = 8; o > 0; o >>= 1) { s += __shfl_xor(s, o); ss += __shfl_xor(ss, o); }
        if (pi == 0) {
            float mu = s / (float)(CPG * NTOK);
            float var = ss / (float)(CPG * NTOK) - mu * mu;
            gmu[gi] = mu;
            grs[gi] = rsqrtf(var + EPS);
        }
    }
    int tt = tid & 31, cr = tid >> 5;
    __syncthreads();
    #pragma unroll
    for (int i = 0; i < 4; ++i) {
        int co = cr + 8 * i;               // 0..31
        int c = c0 + co;
        float mu = gmu[co >> 4], rs = grs[co >> 4];
        float v = x[((size_t)(b * C + c)) * NTOK + t0 + tt];
        tile[co][tt] = (v - mu) * rs * gamma[c] + beta[c];
    }
    __syncthreads();
    #pragma unroll
    for (int i = 0; i < 4; ++i) {
        int t = t0 + cr + 8 * i;
        int c = c0 + tt;
        xn[((size_t)b * NTOK + t) * C + c] = f2b(tile[tt][cr + 8 * i]);
    }
}

// ---------------------------------------------------------------------------
// All 4 weight transpose+casts in one launch: out[n][k] = in[k][n].
// z: 0=Wq(512x512), 1=Wk(768x512), 2=Wv(768x512), 3=Wo(512x512).
__global__ __launch_bounds__(256) void wcast_all_kernel(
    const float* __restrict__ Wq, const float* __restrict__ Wk,
    const float* __restrict__ Wv, const float* __restrict__ Wo,
    bf16_t* __restrict__ Wqt, bf16_t* __restrict__ Wkvt, bf16_t* __restrict__ Wot) {
    int z = blockIdx.z;
    const float* in; bf16_t* out; int K;
    if (z == 0)      { in = Wq; out = Wqt;  K = C; }
    else if (z == 1) { in = Wk; out = Wkvt; K = CDIM; }
    else if (z == 2) { in = Wv; out = Wkvt + (size_t)INNER * CDIM; K = CDIM; }
    else             { in = Wo; out = Wot;  K = INNER; }
    int k0 = blockIdx.x * 32, n0 = blockIdx.y * 32;
    if (k0 >= K) return;
    __shared__ float t[32][33];
    int xx = threadIdx.x & 31, yy = threadIdx.x >> 5;
    #pragma unroll
    for (int i = 0; i < 4; ++i)
        t[yy + 8 * i][xx] = in[(size_t)(k0 + yy + 8 * i) * INNER + n0 + xx];
    __syncthreads();
    #pragma unroll
    for (int i = 0; i < 4; ++i)
        out[(size_t)(n0 + yy + 8 * i) * K + k0 + xx] = f2b(t[xx][yy + 8 * i]);
}

// ---------------------------------------------------------------------------
// MFMA GEMM, 64x64 tile, 4 waves (2x2), BK=32, reg-prefetch 2-phase loop.
// C = A[M][K] @ Bt[N][K]^T.  AFP32: A is fp32 (context), cast during staging.
// Epilogue scatters bf16*oscale to head-major [bidx][h][seq][d]; cols >= 512
// go to outV ([bidx][h][d][seq] when vtrans).
template <int AFP32>
__global__ __launch_bounds__(256) void gemm_qkv_kernel(
    const void* __restrict__ Av, const bf16_t* __restrict__ Bt,
    bf16_t* __restrict__ outK, bf16_t* __restrict__ outV,
    int K, int seqshift, float oscale, int vtrans) {
    __shared__ __align__(16) bf16_t As[64][40];
    __shared__ __align__(16) bf16_t Bs[64][40];
    const int tid = threadIdx.x;
    const int l = tid & 63, w = tid >> 6;
    const int wr = w >> 1, wc = w & 1;
    const int lg = l >> 4, lr = l & 15;
    const int m0 = blockIdx.x * 64, n0 = blockIdx.y * 64;
    const int rowS = tid >> 2, c8 = (tid & 3) * 8;
    const bf16_t* pa16 = AFP32 ? nullptr : (const bf16_t*)Av + (size_t)(m0 + rowS) * K + c8;
    const float*  pa32 = AFP32 ? (const float*)Av + (size_t)(m0 + rowS) * K + c8 : nullptr;
    const bf16_t* pb = Bt + (size_t)(n0 + rowS) * K + c8;
    f32x4 acc[2][2] = {};
    float av[8];
    float4 ra, rb;
    if (AFP32) {
        *(float4*)&av[0] = *(const float4*)pa32;
        *(float4*)&av[4] = *(const float4*)(pa32 + 4);
        ra = pack8(av);
    } else {
        ra = *(const float4*)pa16;
    }
    rb = *(const float4*)pb;
    *(float4*)&As[rowS][c8] = ra;
    *(float4*)&Bs[rowS][c8] = rb;
    for (int k0 = 0; k0 < K; k0 += 32) {
        __syncthreads();
        if (k0 + 32 < K) {                          // prefetch next K-step
            if (AFP32) {
                *(float4*)&av[0] = *(const float4*)(pa32 + k0 + 32);
                *(float4*)&av[4] = *(const float4*)(pa32 + k0 + 36);
                ra = pack8(av);
            } else {
                ra = *(const float4*)(pa16 + k0 + 32);
            }
            rb = *(const float4*)(pb + k0 + 32);
        }
        bf16x8 af[2], bfm[2];
        af[0]  = *(bf16x8*)&As[wr * 32 + lr][lg * 8];
        af[1]  = *(bf16x8*)&As[wr * 32 + 16 + lr][lg * 8];
        bfm[0] = *(bf16x8*)&Bs[wc * 32 + lr][lg * 8];
        bfm[1] = *(bf16x8*)&Bs[wc * 32 + 16 + lr][lg * 8];
        #pragma unroll
        for (int mi = 0; mi < 2; ++mi)
            #pragma unroll
            for (int ni = 0; ni < 2; ++ni)
                acc[mi][ni] = __builtin_amdgcn_mfma_f32_16x16x32_bf16(af[mi], bfm[ni], acc[mi][ni], 0, 0, 0);
        __syncthreads();
        if (k0 + 32 < K) {
            *(float4*)&As[rowS][c8] = ra;
            *(float4*)&Bs[rowS][c8] = rb;
        }
    }
    const int seqmask = (1 << seqshift) - 1;
    #pragma unroll
    for (int ni = 0; ni < 2; ++ni) {
        int n = n0 + wc * 32 + ni * 16 + lr;
        int nn = n & (INNER - 1);
        int h = nn >> 6, dd = nn & 63;
        bool isV = (n >= INNER);
        #pragma unroll
        for (int mi = 0; mi < 2; ++mi) {
            int mb = m0 + wr * 32 + mi * 16 + lg * 4;
            int bidx = mb >> seqshift, seqb = mb & seqmask;
            if (isV && vtrans) {
                ushort4 pv;                          // 4 consecutive seq packed
                pv.x = f2b(acc[mi][ni][0] * oscale);
                pv.y = f2b(acc[mi][ni][1] * oscale);
                pv.z = f2b(acc[mi][ni][2] * oscale);
                pv.w = f2b(acc[mi][ni][3] * oscale);
                *(ushort4*)&outV[((size_t)(bidx * NH + h) * HD + dd) * (size_t)(seqmask + 1) + seqb] = pv;
            } else {
                bf16_t* dst = isV ? outV : outK;
                #pragma unroll
                for (int r = 0; r < 4; ++r)
                    dst[(((size_t)(bidx * NH + h) << seqshift) + seqb + r) * HD + dd] =
                        f2b(acc[mi][ni][r] * oscale);
            }
        }
    }
}

// O-projection GEMM (K=512), 64x64 tile + prefetch; epilogue bias + residual
// + transpose to fp32 out[b][c][t] with float4 stores.
__global__ __launch_bounds__(256) void gemm_o_kernel(
    const bf16_t* __restrict__ A, const bf16_t* __restrict__ Bt,
    const float* __restrict__ bo, const float* __restrict__ x,
    float* __restrict__ out) {
    __shared__ __align__(16) bf16_t As[64][40];
    __shared__ __align__(16) bf16_t Bs[64][40];
    const int tid = threadIdx.x;
    const int l = tid & 63, w = tid >> 6;
    const int wr = w >> 1, wc = w & 1;
    const int lg = l >> 4, lr = l & 15;
    const int m0 = blockIdx.x * 64, n0 = blockIdx.y * 64;
    const int rowS = tid >> 2, c8 = (tid & 3) * 8;
    const bf16_t* pa = A  + (size_t)(m0 + rowS) * INNER + c8;
    const bf16_t* pb = Bt + (size_t)(n0 + rowS) * INNER + c8;
    f32x4 acc[2][2] = {};
    float4 ra = *(const float4*)pa;
    float4 rb = *(const float4*)pb;
    *(float4*)&As[rowS][c8] = ra;
    *(float4*)&Bs[rowS][c8] = rb;
    for (int k0 = 0; k0 < INNER; k0 += 32) {
        __syncthreads();
        if (k0 + 32 < INNER) {
            ra = *(const float4*)(pa + k0 + 32);
            rb = *(const float4*)(pb + k0 + 32);
        }
        bf16x8 af[2], bfm[2];
        af[0]  = *(bf16x8*)&As[wr * 32 + lr][lg * 8];
        af[1]  = *(bf16x8*)&As[wr * 32 + 16 + lr][lg * 8];
        bfm[0] = *(bf16x8*)&Bs[wc * 32 + lr][lg * 8];
        bfm[1] = *(bf16x8*)&Bs[wc * 32 + 16 + lr][lg * 8];
        #pragma unroll
        for (int mi = 0; mi < 2; ++mi)
            #pragma unroll
            for (int ni = 0; ni < 2; ++ni)
                acc[mi][ni] = __builtin_amdgcn_mfma_f32_16x16x32_bf16(af[mi], bfm[ni], acc[mi][ni], 0, 0, 0);
        __syncthreads();
        if (k0 + 32 < INNER) {
            *(float4*)&As[rowS][c8] = ra;
            *(float4*)&Bs[rowS][c8] = rb;
        }
    }
    #pragma unroll
    for (int mi = 0; mi < 2; ++mi) {
        int mb = m0 + wr * 32 + mi * 16 + lg * 4;   // 4 consecutive t
        int t = mb & (NTOK - 1);
        int bb = mb >> 12;
        #pragma unroll
        for (int ni = 0; ni < 2; ++ni) {
            int cc = n0 + wc * 32 + ni * 16 + lr;
            size_t o = (((size_t)(bb * C + cc)) << 12) + t;
            float4 xr = *(const float4*)&x[o];
            float bias = bo[cc];
            float4 ov;
            ov.x = acc[mi][ni][0] + bias + xr.x;
            ov.y = acc[mi][ni][1] + bias + xr.y;
            ov.z = acc[mi][ni][2] + bias + xr.z;
            ov.w = acc[mi][ni][3] + bias + xr.w;
            *(float4*)&out[o] = ov;
        }
    }
}

// ---------------------------------------------------------------------------
// Flash attention. 4 waves x 16 q-rows (64 q/block, 1024 blocks for TLP);
// K [bh][key][d], V pre-transposed [bh][d][key]. Swizzled LDS, reg-prefetched
// chunks, 2 barriers/chunk. Q pre-scaled by HD^-0.5 * log2(e): softmax runs
// in exp2 domain (raw v_exp_f32, no multiply).
__global__ __launch_bounds__(256) void attn_kernel(
    const bf16_t* __restrict__ Q, const bf16_t* __restrict__ Kb,
    const bf16_t* __restrict__ Vt, bf16_t* __restrict__ AO) {
    __shared__ __align__(16) bf16_t Ks[64 * 64];    // [key][d] swizzled, 8 KB
    __shared__ __align__(16) bf16_t Vs[64 * 64];    // [d][key] swizzled, 8 KB
    __shared__ __align__(16) bf16_t Ps[4][16 * 64]; // per-wave P [qrow][key], 8 KB
    const int tid = threadIdx.x;
    const int l = tid & 63, w = tid >> 6;
    const int lg = l >> 4, lr = l & 15;
    const int bh = blockIdx.x >> 6;                 // b*8+h
    const int tile = blockIdx.x & 63;
    const int b = bh >> 3, h = bh & 7;
    const int t0 = tile * 64 + w * 16;

    const bf16_t* qbase = Q + ((size_t)bh * NTOK + t0 + lr) * HD;
    bf16x8 qf[2];
    qf[0] = *(const bf16x8*)&qbase[lg * 8];
    qf[1] = *(const bf16x8*)&qbase[32 + lg * 8];

    f32x4 acc[4] = {};                              // O cols d = ni*16+lr, rows 4*lg+r
    float mrow[4], lrow[4];
    #pragma unroll
    for (int r = 0; r < 4; ++r) { mrow[r] = -1e30f; lrow[r] = 0.f; }

    const bf16_t* kbase = Kb + (size_t)bh * CTX * HD;
    const bf16_t* vbase = Vt + (size_t)bh * HD * CTX;
    const int srow = tid >> 3, sc8 = (tid & 7) * 8;

    float4 kr0 = *(const float4*)&kbase[(size_t)srow * HD + sc8];
    float4 kr1 = *(const float4*)&kbase[(size_t)(srow + 32) * HD + sc8];
    float4 vr0 = *(const float4*)&vbase[(size_t)srow * CTX + sc8];
    float4 vr1 = *(const float4*)&vbase[(size_t)(srow + 32) * CTX + sc8];
    *(float4*)&Ks[swz(srow, sc8)] = kr0;
    *(float4*)&Ks[swz(srow + 32, sc8)] = kr1;
    *(float4*)&Vs[swz(srow, sc8)] = vr0;
    *(float4*)&Vs[swz(srow + 32, sc8)] = vr1;

    for (int c = 0; c < NCH; ++c) {
        __syncthreads();                            // chunk c staged
        if (c + 1 < NCH) {                          // prefetch chunk c+1 to regs
            int k1 = (c + 1) * KVBLK;
            kr0 = *(const float4*)&kbase[(size_t)(k1 + srow) * HD + sc8];
            kr1 = *(const float4*)&kbase[(size_t)(k1 + srow + 32) * HD + sc8];
            vr0 = *(const float4*)&vbase[(size_t)srow * CTX + k1 + sc8];
            vr1 = *(const float4*)&vbase[(size_t)(srow + 32) * CTX + k1 + sc8];
        }
        // QK^T: S[16 q-rows][64 keys] (log2-domain scores)
        f32x4 sf[4] = {};
        #pragma unroll
        for (int ks = 0; ks < 2; ++ks)
            #pragma unroll
            for (int ni = 0; ni < 4; ++ni) {
                bf16x8 kf = *(bf16x8*)&Ks[swz(ni * 16 + lr, ks * 32 + lg * 8)];
                sf[ni] = __builtin_amdgcn_mfma_f32_16x16x32_bf16(qf[ks], kf, sf[ni], 0, 0, 0);
            }
        // Online softmax in exp2 domain (rows 4*lg+r; reduce over 16-lane group)
        #pragma unroll
        for (int r = 0; r < 4; ++r) {
            float s0 = sf[0][r], s1 = sf[1][r];
            float s2 = sf[2][r], s3 = sf[3][r];
            float cm = fmaxf(fmaxf(s0, s1), fmaxf(s2, s3));
            cm = fmaxf(cm, __shfl_xor(cm, 1));
            cm = fmaxf(cm, __shfl_xor(cm, 2));
            cm = fmaxf(cm, __shfl_xor(cm, 4));
            cm = fmaxf(cm, __shfl_xor(cm, 8));
            float mn = fmaxf(mrow[r], cm);
            float scl = __builtin_amdgcn_exp2f(mrow[r] - mn);
            float p0 = __builtin_amdgcn_exp2f(s0 - mn);
            float p1 = __builtin_amdgcn_exp2f(s1 - mn);
            float p2 = __builtin_amdgcn_exp2f(s2 - mn);
            float p3 = __builtin_amdgcn_exp2f(s3 - mn);
            float rs = p0 + p1 + p2 + p3;
            rs += __shfl_xor(rs, 1); rs += __shfl_xor(rs, 2);
            rs += __shfl_xor(rs, 4); rs += __shfl_xor(rs, 8);
            lrow[r] = lrow[r] * scl + rs;
            mrow[r] = mn;
            #pragma unroll
            for (int ni = 0; ni < 4; ++ni) acc[ni][r] *= scl;
            int prow = lg * 4 + r;
            Ps[w][swz(prow, 0 * 16 + lr)] = f2b(p0);
            Ps[w][swz(prow, 1 * 16 + lr)] = f2b(p1);
            Ps[w][swz(prow, 2 * 16 + lr)] = f2b(p2);
            Ps[w][swz(prow, 3 * 16 + lr)] = f2b(p3);
        }
        // PV (Ps is wave-private: in-wave DS ordering suffices, no barrier)
        #pragma unroll
        for (int ks = 0; ks < 2; ++ks) {
            bf16x8 pf = *(bf16x8*)&Ps[w][swz(lr, ks * 32 + lg * 8)];
            #pragma unroll
            for (int ni = 0; ni < 4; ++ni) {
                bf16x8 vf = *(bf16x8*)&Vs[swz(ni * 16 + lr, ks * 32 + lg * 8)];
                acc[ni] = __builtin_amdgcn_mfma_f32_16x16x32_bf16(pf, vf, acc[ni], 0, 0, 0);
            }
        }
        __syncthreads();                            // all reads of chunk c done
        if (c + 1 < NCH) {
            *(float4*)&Ks[swz(srow, sc8)] = kr0;
            *(float4*)&Ks[swz(srow + 32, sc8)] = kr1;
            *(float4*)&Vs[swz(srow, sc8)] = vr0;
            *(float4*)&Vs[swz(srow + 32, sc8)] = vr1;
        }
    }

    #pragma unroll
    for (int ni = 0; ni < 4; ++ni)
        #pragma unroll
        for (int r = 0; r < 4; ++r) {
            int t = t0 + lg * 4 + r;
            AO[((size_t)b * NTOK + t) * INNER + h * HD + ni * 16 + lr] =
                f2b(acc[ni][r] / lrow[r]);
        }
}

// ---------------------------------------------------------------------------
extern "C" void kernel_launch(void* const* d_in, const int* in_sizes, int n_in,
                              void* d_out, int out_size, void* d_ws, size_t ws_size,
                              hipStream_t stream) {
    const float* x       = (const float*)d_in[0];
    const float* context = (const float*)d_in[1];
    const float* gamma   = (const float*)d_in[2];
    const float* beta    = (const float*)d_in[3];
    const float* Wq      = (const float*)d_in[4];
    const float* Wk      = (const float*)d_in[5];
    const float* Wv      = (const float*)d_in[6];
    const float* Wo      = (const float*)d_in[7];
    const float* bo      = (const float*)d_in[8];
    float* out = (float*)d_out;

    char* p = (char*)d_ws;
    float2* parts = (float2*)p;          p += 1024 * sizeof(float2);
    bf16_t* xn   = (bf16_t*)p;           p += (size_t)B * NTOK * C * 2;      // 8 MB
    bf16_t* Wqt  = (bf16_t*)p;           p += (size_t)INNER * C * 2;
    bf16_t* Wkvt = (bf16_t*)p;           p += (size_t)2 * INNER * CDIM * 2;
    bf16_t* Wot  = (bf16_t*)p;           p += (size_t)C * INNER * 2;
    bf16_t* qb   = (bf16_t*)p;           p += (size_t)B * NH * NTOK * HD * 2;
    bf16_t* kb   = (bf16_t*)p;           p += (size_t)B * NH * CTX * HD * 2;
    bf16_t* vb   = (bf16_t*)p;           p += (size_t)B * NH * CTX * HD * 2; // V^T [b,h,d,key]
    bf16_t* ao   = (bf16_t*)p;           p += (size_t)B * NTOK * INNER * 2;

    hipLaunchKernelGGL(gn_partial_kernel, dim3(B * C), dim3(256), 0, stream, x, parts);
    hipLaunchKernelGGL(gn_apply_kernel, dim3(NTOK / 32, C / 32, B), dim3(256), 0, stream,
                       x, parts, gamma, beta, xn);
    hipLaunchKernelGGL(wcast_all_kernel, dim3(24, 16, 4), dim3(256), 0, stream,
                       Wq, Wk, Wv, Wo, Wqt, Wkvt, Wot);
    // Q = xn @ Wq, pre-scaled by HD^-0.5 * log2(e)  (M=8192, K=512, N=512)
    hipLaunchKernelGGL((gemm_qkv_kernel<0>), dim3(128, 8), dim3(256), 0, stream,
                       (const void*)xn, Wqt, qb, qb, C, 12, 0.125f * LOG2E, 0);
    // K|V = ctx @ [Wk|Wv]; A staged from fp32 directly; V written transposed
    hipLaunchKernelGGL((gemm_qkv_kernel<1>), dim3(32, 16), dim3(256), 0, stream,
                       (const void*)context, Wkvt, kb, vb, CDIM, 10, 1.0f, 1);
    hipLaunchKernelGGL(attn_kernel, dim3(B * NH * (NTOK / 64)), dim3(256), 0, stream,
                       qb, kb, vb, ao);
    hipLaunchKernelGGL(gemm_o_kernel, dim3(128, 8), dim3(256), 0, stream,
                       ao, Wot, bo, x, out);
}

// Round 8
// 171.511 us; speedup vs baseline: 8.8294x; 1.1353x over previous
//
#include <hip/hip_runtime.h>
#include <hip/hip_bf16.h>

#define B 2
#define C 512
#define NTOK 4096          // d*w*hs
#define GROUPS 32
#define CPG 16
#define CTX 1024
#define CDIM 768
#define NH 8
#define HD 64
#define INNER 512
#define EPS 1e-5f
#define KVBLK 64
#define NCH (CTX / KVBLK)  // 16
#define LOG2E 1.44269504f

typedef unsigned short bf16_t;
typedef __attribute__((ext_vector_type(8))) short bf16x8;   // 8 bf16 = 4 VGPRs (MFMA A/B frag)
typedef __attribute__((ext_vector_type(4))) float f32x4;    // MFMA C/D frag

__device__ __forceinline__ bf16_t f2b(float f) {
    unsigned u = __float_as_uint(f);
    u += 0x7fffu + ((u >> 16) & 1u);          // RNE
    return (bf16_t)(u >> 16);
}

// pack 8 fp32 -> 8 bf16 in a float4-sized container (for 16B LDS stores)
__device__ __forceinline__ float4 pack8(const float* v) {
    union { ushort s[8]; float4 f; } u;
    #pragma unroll
    for (int j = 0; j < 8; ++j) u.s[j] = f2b(v[j]);
    return u.f;
}

// v_cvt_pk_bf16_f32: D[15:0]=bf16(lo), D[31:16]=bf16(hi)  (guide T12, m214v22)
__device__ __forceinline__ unsigned cvtpk(float lo, float hi) {
    unsigned r;
    asm("v_cvt_pk_bf16_f32 %0, %1, %2" : "=v"(r) : "v"(lo), "v"(hi));
    return r;
}

// XOR-swizzle for 64-col bf16 LDS tiles (row stride 128 B): spreads the
// 16-B slot of each row across 8 slots -> conflict-free b128 col-reads.
// XOR touches only bits >=3, so 4-elem (8B) and 8-elem (16B) groups at
// 4/8-aligned col bases stay contiguous.
__device__ __forceinline__ int swz(int row, int col) {
    return row * 64 + (col ^ ((row & 7) << 3));
}

// ---------------------------------------------------------------------------
// GroupNorm stats, stage 1: 1024 blocks (= one channel each), float4 loads ->
// one float2 partial (sum, sumsq) per channel.  partials[b*C + c].
__global__ __launch_bounds__(256) void gn_partial_kernel(const float* __restrict__ x,
                                                         float2* __restrict__ partials) {
    int blk = blockIdx.x;                 // 0..B*C-1
    const float* base = x + (size_t)blk * 4096;
    float s = 0.f, ss = 0.f;
    #pragma unroll
    for (int i = 0; i < 4; ++i) {
        float4 v = *(const float4*)&base[(threadIdx.x + i * 256) * 4];
        s += v.x + v.y + v.z + v.w;
        ss += v.x * v.x + v.y * v.y + v.z * v.z + v.w * v.w;
    }
    #pragma unroll
    for (int o = 32; o > 0; o >>= 1) { s += __shfl_xor(s, o); ss += __shfl_xor(ss, o); }
    __shared__ float ls[2][4];
    int wv = threadIdx.x >> 6, ln = threadIdx.x & 63;
    if (ln == 0) { ls[0][wv] = s; ls[1][wv] = ss; }
    __syncthreads();
    if (threadIdx.x == 0) {
        partials[blk] = make_float2(ls[0][0] + ls[0][1] + ls[0][2] + ls[0][3],
                                    ls[1][0] + ls[1][1] + ls[1][2] + ls[1][3]);
    }
}

// ---------------------------------------------------------------------------
// Apply GroupNorm + transpose to bf16 xn[b][t][c].  Finalizes the 2 groups'
// stats it needs from the per-channel partials (gn_finalize fused away).
__global__ __launch_bounds__(256) void gn_apply_kernel(const float* __restrict__ x,
                                                       const float2* __restrict__ partials,
                                                       const float* __restrict__ gamma,
                                                       const float* __restrict__ beta,
                                                       bf16_t* __restrict__ xn) {
    __shared__ float tile[32][33];
    __shared__ float gmu[2], grs[2];
    int b = blockIdx.z;
    int c0 = blockIdx.y * 32;
    int t0 = blockIdx.x * 32;
    int tid = threadIdx.x;
    if (tid < 32) {                        // finalize the 2 groups covering c0..c0+31
        int gi = tid >> 4, pi = tid & 15;
        float2 pp = partials[b * C + c0 + gi * 16 + pi];
        float s = pp.x, ss = pp.y;
        #pragma unroll
        for (int o = 8; o > 0; o >>= 1) { s += __shfl_xor(s, o); ss += __shfl_xor(ss, o); }
        if (pi == 0) {
            float mu = s / (float)(CPG * NTOK);
            float var = ss / (float)(CPG * NTOK) - mu * mu;
            gmu[gi] = mu;
            grs[gi] = rsqrtf(var + EPS);
        }
    }
    int tt = tid & 31, cr = tid >> 5;
    __syncthreads();
    #pragma unroll
    for (int i = 0; i < 4; ++i) {
        int co = cr + 8 * i;               // 0..31
        int c = c0 + co;
        float mu = gmu[co >> 4], rs = grs[co >> 4];
        float v = x[((size_t)(b * C + c)) * NTOK + t0 + tt];
        tile[co][tt] = (v - mu) * rs * gamma[c] + beta[c];
    }
    __syncthreads();
    #pragma unroll
    for (int i = 0; i < 4; ++i) {
        int t = t0 + cr + 8 * i;
        int c = c0 + tt;
        xn[((size_t)b * NTOK + t) * C + c] = f2b(tile[tt][cr + 8 * i]);
    }
}

// ---------------------------------------------------------------------------
// All 4 weight transpose+casts in one launch: out[n][k] = in[k][n].
// z: 0=Wq(512x512), 1=Wk(768x512), 2=Wv(768x512), 3=Wo(512x512).
__global__ __launch_bounds__(256) void wcast_all_kernel(
    const float* __restrict__ Wq, const float* __restrict__ Wk,
    const float* __restrict__ Wv, const float* __restrict__ Wo,
    bf16_t* __restrict__ Wqt, bf16_t* __restrict__ Wkvt, bf16_t* __restrict__ Wot) {
    int z = blockIdx.z;
    const float* in; bf16_t* out; int K;
    if (z == 0)      { in = Wq; out = Wqt;  K = C; }
    else if (z == 1) { in = Wk; out = Wkvt; K = CDIM; }
    else if (z == 2) { in = Wv; out = Wkvt + (size_t)INNER * CDIM; K = CDIM; }
    else             { in = Wo; out = Wot;  K = INNER; }
    int k0 = blockIdx.x * 32, n0 = blockIdx.y * 32;
    if (k0 >= K) return;
    __shared__ float t[32][33];
    int xx = threadIdx.x & 31, yy = threadIdx.x >> 5;
    #pragma unroll
    for (int i = 0; i < 4; ++i)
        t[yy + 8 * i][xx] = in[(size_t)(k0 + yy + 8 * i) * INNER + n0 + xx];
    __syncthreads();
    #pragma unroll
    for (int i = 0; i < 4; ++i)
        out[(size_t)(n0 + yy + 8 * i) * K + k0 + xx] = f2b(t[xx][yy + 8 * i]);
}

// ---------------------------------------------------------------------------
// MFMA GEMM, 64x64 tile, 4 waves (2x2), BK=32, reg-prefetch 2-phase loop.
// C = A[M][K] @ Bt[N][K]^T.  AFP32: A is fp32 (context), cast during staging.
// Epilogue scatters bf16*oscale to head-major [bidx][h][seq][d]; cols >= 512
// go to outV ([bidx][h][d][seq] when vtrans).
template <int AFP32>
__global__ __launch_bounds__(256) void gemm_qkv_kernel(
    const void* __restrict__ Av, const bf16_t* __restrict__ Bt,
    bf16_t* __restrict__ outK, bf16_t* __restrict__ outV,
    int K, int seqshift, float oscale, int vtrans) {
    __shared__ __align__(16) bf16_t As[64][40];
    __shared__ __align__(16) bf16_t Bs[64][40];
    const int tid = threadIdx.x;
    const int l = tid & 63, w = tid >> 6;
    const int wr = w >> 1, wc = w & 1;
    const int lg = l >> 4, lr = l & 15;
    const int m0 = blockIdx.x * 64, n0 = blockIdx.y * 64;
    const int rowS = tid >> 2, c8 = (tid & 3) * 8;
    const bf16_t* pa16 = AFP32 ? nullptr : (const bf16_t*)Av + (size_t)(m0 + rowS) * K + c8;
    const float*  pa32 = AFP32 ? (const float*)Av + (size_t)(m0 + rowS) * K + c8 : nullptr;
    const bf16_t* pb = Bt + (size_t)(n0 + rowS) * K + c8;
    f32x4 acc[2][2] = {};
    float av[8];
    float4 ra, rb;
    if (AFP32) {
        *(float4*)&av[0] = *(const float4*)pa32;
        *(float4*)&av[4] = *(const float4*)(pa32 + 4);
        ra = pack8(av);
    } else {
        ra = *(const float4*)pa16;
    }
    rb = *(const float4*)pb;
    *(float4*)&As[rowS][c8] = ra;
    *(float4*)&Bs[rowS][c8] = rb;
    for (int k0 = 0; k0 < K; k0 += 32) {
        __syncthreads();
        if (k0 + 32 < K) {                          // prefetch next K-step
            if (AFP32) {
                *(float4*)&av[0] = *(const float4*)(pa32 + k0 + 32);
                *(float4*)&av[4] = *(const float4*)(pa32 + k0 + 36);
                ra = pack8(av);
            } else {
                ra = *(const float4*)(pa16 + k0 + 32);
            }
            rb = *(const float4*)(pb + k0 + 32);
        }
        bf16x8 af[2], bfm[2];
        af[0]  = *(bf16x8*)&As[wr * 32 + lr][lg * 8];
        af[1]  = *(bf16x8*)&As[wr * 32 + 16 + lr][lg * 8];
        bfm[0] = *(bf16x8*)&Bs[wc * 32 + lr][lg * 8];
        bfm[1] = *(bf16x8*)&Bs[wc * 32 + 16 + lr][lg * 8];
        #pragma unroll
        for (int mi = 0; mi < 2; ++mi)
            #pragma unroll
            for (int ni = 0; ni < 2; ++ni)
                acc[mi][ni] = __builtin_amdgcn_mfma_f32_16x16x32_bf16(af[mi], bfm[ni], acc[mi][ni], 0, 0, 0);
        __syncthreads();
        if (k0 + 32 < K) {
            *(float4*)&As[rowS][c8] = ra;
            *(float4*)&Bs[rowS][c8] = rb;
        }
    }
    const int seqmask = (1 << seqshift) - 1;
    #pragma unroll
    for (int ni = 0; ni < 2; ++ni) {
        int n = n0 + wc * 32 + ni * 16 + lr;
        int nn = n & (INNER - 1);
        int h = nn >> 6, dd = nn & 63;
        bool isV = (n >= INNER);
        #pragma unroll
        for (int mi = 0; mi < 2; ++mi) {
            int mb = m0 + wr * 32 + mi * 16 + lg * 4;
            int bidx = mb >> seqshift, seqb = mb & seqmask;
            if (isV && vtrans) {
                ushort4 pv;                          // 4 consecutive seq packed
                pv.x = f2b(acc[mi][ni][0] * oscale);
                pv.y = f2b(acc[mi][ni][1] * oscale);
                pv.z = f2b(acc[mi][ni][2] * oscale);
                pv.w = f2b(acc[mi][ni][3] * oscale);
                *(ushort4*)&outV[((size_t)(bidx * NH + h) * HD + dd) * (size_t)(seqmask + 1) + seqb] = pv;
            } else {
                bf16_t* dst = isV ? outV : outK;
                #pragma unroll
                for (int r = 0; r < 4; ++r)
                    dst[(((size_t)(bidx * NH + h) << seqshift) + seqb + r) * HD + dd] =
                        f2b(acc[mi][ni][r] * oscale);
            }
        }
    }
}

// O-projection GEMM (K=512), 64x64 tile + prefetch; epilogue bias + residual
// + transpose to fp32 out[b][c][t] with float4 stores.
__global__ __launch_bounds__(256) void gemm_o_kernel(
    const bf16_t* __restrict__ A, const bf16_t* __restrict__ Bt,
    const float* __restrict__ bo, const float* __restrict__ x,
    float* __restrict__ out) {
    __shared__ __align__(16) bf16_t As[64][40];
    __shared__ __align__(16) bf16_t Bs[64][40];
    const int tid = threadIdx.x;
    const int l = tid & 63, w = tid >> 6;
    const int wr = w >> 1, wc = w & 1;
    const int lg = l >> 4, lr = l & 15;
    const int m0 = blockIdx.x * 64, n0 = blockIdx.y * 64;
    const int rowS = tid >> 2, c8 = (tid & 3) * 8;
    const bf16_t* pa = A  + (size_t)(m0 + rowS) * INNER + c8;
    const bf16_t* pb = Bt + (size_t)(n0 + rowS) * INNER + c8;
    f32x4 acc[2][2] = {};
    float4 ra = *(const float4*)pa;
    float4 rb = *(const float4*)pb;
    *(float4*)&As[rowS][c8] = ra;
    *(float4*)&Bs[rowS][c8] = rb;
    for (int k0 = 0; k0 < INNER; k0 += 32) {
        __syncthreads();
        if (k0 + 32 < INNER) {
            ra = *(const float4*)(pa + k0 + 32);
            rb = *(const float4*)(pb + k0 + 32);
        }
        bf16x8 af[2], bfm[2];
        af[0]  = *(bf16x8*)&As[wr * 32 + lr][lg * 8];
        af[1]  = *(bf16x8*)&As[wr * 32 + 16 + lr][lg * 8];
        bfm[0] = *(bf16x8*)&Bs[wc * 32 + lr][lg * 8];
        bfm[1] = *(bf16x8*)&Bs[wc * 32 + 16 + lr][lg * 8];
        #pragma unroll
        for (int mi = 0; mi < 2; ++mi)
            #pragma unroll
            for (int ni = 0; ni < 2; ++ni)
                acc[mi][ni] = __builtin_amdgcn_mfma_f32_16x16x32_bf16(af[mi], bfm[ni], acc[mi][ni], 0, 0, 0);
        __syncthreads();
        if (k0 + 32 < INNER) {
            *(float4*)&As[rowS][c8] = ra;
            *(float4*)&Bs[rowS][c8] = rb;
        }
    }
    #pragma unroll
    for (int mi = 0; mi < 2; ++mi) {
        int mb = m0 + wr * 32 + mi * 16 + lg * 4;   // 4 consecutive t
        int t = mb & (NTOK - 1);
        int bb = mb >> 12;
        #pragma unroll
        for (int ni = 0; ni < 2; ++ni) {
            int cc = n0 + wc * 32 + ni * 16 + lr;
            size_t o = (((size_t)(bb * C + cc)) << 12) + t;
            float4 xr = *(const float4*)&x[o];
            float bias = bo[cc];
            float4 ov;
            ov.x = acc[mi][ni][0] + bias + xr.x;
            ov.y = acc[mi][ni][1] + bias + xr.y;
            ov.z = acc[mi][ni][2] + bias + xr.z;
            ov.w = acc[mi][ni][3] + bias + xr.w;
            *(float4*)&out[o] = ov;
        }
    }
}

// ---------------------------------------------------------------------------
// Flash attention with SWAPPED QK^T (T12): S^T = mfma(A=K, B=Q) puts 4
// adjacent keys x one q-row (q=lr) in each lane -> row reduce is in-lane +
// 2 shfls; P packs to adjacent keys (cvt_pk + b64 write, 4 writes vs 16
// scalar). DS-pipe load per chunk drops ~45%. 4 waves x 16 q-rows; K
// [bh][key][d], V pre-transposed [bh][d][key]; swizzled LDS; reg-prefetch;
// Q pre-scaled by HD^-0.5*log2(e) (exp2-domain softmax).
__global__ __launch_bounds__(256) void attn_kernel(
    const bf16_t* __restrict__ Q, const bf16_t* __restrict__ Kb,
    const bf16_t* __restrict__ Vt, bf16_t* __restrict__ AO) {
    __shared__ __align__(16) bf16_t Ks[64 * 64];    // [key][d] swizzled, 8 KB
    __shared__ __align__(16) bf16_t Vs[64 * 64];    // [d][key] swizzled, 8 KB
    __shared__ __align__(16) bf16_t Ps[4][16 * 64]; // per-wave P [q][key] swz, 8 KB
    const int tid = threadIdx.x;
    const int l = tid & 63, w = tid >> 6;
    const int lg = l >> 4, lr = l & 15;
    const int bh = blockIdx.x >> 6;                 // b*8+h
    const int tile = blockIdx.x & 63;
    const int b = bh >> 3, h = bh & 7;
    const int t0 = tile * 64 + w * 16;

    // Q fragments (used as the B operand now; same per-lane data as A-frag)
    const bf16_t* qbase = Q + ((size_t)bh * NTOK + t0 + lr) * HD;
    bf16x8 qf[2];
    qf[0] = *(const bf16x8*)&qbase[lg * 8];
    qf[1] = *(const bf16x8*)&qbase[32 + lg * 8];

    f32x4 acc[4] = {};          // acc[ni][r] = O[q=4*lg+r][d=ni*16+lr]
    float mrow = -1e30f;        // running max for q = lr (scalar per lane)
    float lrow = 0.f;           // running denom for q = lr

    const bf16_t* kbase = Kb + (size_t)bh * CTX * HD;
    const bf16_t* vbase = Vt + (size_t)bh * HD * CTX;
    const int srow = tid >> 3, sc8 = (tid & 7) * 8;

    float4 kr0 = *(const float4*)&kbase[(size_t)srow * HD + sc8];
    float4 kr1 = *(const float4*)&kbase[(size_t)(srow + 32) * HD + sc8];
    float4 vr0 = *(const float4*)&vbase[(size_t)srow * CTX + sc8];
    float4 vr1 = *(const float4*)&vbase[(size_t)(srow + 32) * CTX + sc8];
    *(float4*)&Ks[swz(srow, sc8)] = kr0;
    *(float4*)&Ks[swz(srow + 32, sc8)] = kr1;
    *(float4*)&Vs[swz(srow, sc8)] = vr0;
    *(float4*)&Vs[swz(srow + 32, sc8)] = vr1;

    for (int c = 0; c < NCH; ++c) {
        __syncthreads();                            // chunk c staged
        if (c + 1 < NCH) {                          // prefetch chunk c+1 to regs
            int k1 = (c + 1) * KVBLK;
            kr0 = *(const float4*)&kbase[(size_t)(k1 + srow) * HD + sc8];
            kr1 = *(const float4*)&kbase[(size_t)(k1 + srow + 32) * HD + sc8];
            vr0 = *(const float4*)&vbase[(size_t)srow * CTX + k1 + sc8];
            vr1 = *(const float4*)&vbase[(size_t)(srow + 32) * CTX + k1 + sc8];
        }
        // Swapped QK^T: sf[ni][r] = S[q=lr][key = ni*16 + 4*lg + r]
        f32x4 sf[4] = {};
        #pragma unroll
        for (int ks = 0; ks < 2; ++ks)
            #pragma unroll
            for (int ni = 0; ni < 4; ++ni) {
                bf16x8 kf = *(bf16x8*)&Ks[swz(ni * 16 + lr, ks * 32 + lg * 8)];
                sf[ni] = __builtin_amdgcn_mfma_f32_16x16x32_bf16(kf, qf[ks], sf[ni], 0, 0, 0);
            }
        // Row reduce: in-lane over 16 values, then across the 4 lg-groups.
        float cm = sf[0][0];
        #pragma unroll
        for (int ni = 0; ni < 4; ++ni)
            #pragma unroll
            for (int r = 0; r < 4; ++r) cm = fmaxf(cm, sf[ni][r]);
        cm = fmaxf(cm, __shfl_xor(cm, 16));
        cm = fmaxf(cm, __shfl_xor(cm, 32));
        float mn = fmaxf(mrow, cm);
        float scl = __builtin_amdgcn_exp2f(mrow - mn);
        mrow = mn;
        float p[4][4];
        float rs = 0.f;
        #pragma unroll
        for (int ni = 0; ni < 4; ++ni)
            #pragma unroll
            for (int r = 0; r < 4; ++r) {
                p[ni][r] = __builtin_amdgcn_exp2f(sf[ni][r] - mn);
                rs += p[ni][r];
            }
        rs += __shfl_xor(rs, 16);
        rs += __shfl_xor(rs, 32);
        lrow = lrow * scl + rs;
        // P -> LDS: keys 4*lg+r are ADJACENT -> pack pairs, one b64 per ni.
        #pragma unroll
        for (int ni = 0; ni < 4; ++ni) {
            unsigned pk0 = cvtpk(p[ni][0], p[ni][1]);
            unsigned pk1 = cvtpk(p[ni][2], p[ni][3]);
            *(uint2*)&Ps[w][swz(lr, ni * 16 + 4 * lg)] = make_uint2(pk0, pk1);
        }
        // Rescale acc rows (q=4*lg+r) with scl fetched from lane lr=4*lg+r.
        float sclr[4];
        #pragma unroll
        for (int r = 0; r < 4; ++r)
            sclr[r] = __shfl(scl, (l & 48) | (4 * lg + r));
        #pragma unroll
        for (int ni = 0; ni < 4; ++ni)
            #pragma unroll
            for (int r = 0; r < 4; ++r) acc[ni][r] *= sclr[r];
        // PV: A-frag = P[q=lr][keys ks*32+8*lg..+7] (b128), B-frag = V^T.
        #pragma unroll
        for (int ks = 0; ks < 2; ++ks) {
            bf16x8 pf = *(bf16x8*)&Ps[w][swz(lr, ks * 32 + 8 * lg)];
            #pragma unroll
            for (int ni = 0; ni < 4; ++ni) {
                bf16x8 vf = *(bf16x8*)&Vs[swz(ni * 16 + lr, ks * 32 + lg * 8)];
                acc[ni] = __builtin_amdgcn_mfma_f32_16x16x32_bf16(pf, vf, acc[ni], 0, 0, 0);
            }
        }
        __syncthreads();                            // all reads of chunk c done
        if (c + 1 < NCH) {
            *(float4*)&Ks[swz(srow, sc8)] = kr0;
            *(float4*)&Ks[swz(srow + 32, sc8)] = kr1;
            *(float4*)&Vs[swz(srow, sc8)] = vr0;
            *(float4*)&Vs[swz(srow + 32, sc8)] = vr1;
        }
    }

    // Final divide: lrow for q=4*lg+r lives on lane lr=4*lg+r.
    float lfin[4];
    #pragma unroll
    for (int r = 0; r < 4; ++r)
        lfin[r] = __shfl(lrow, (l & 48) | (4 * lg + r));
    #pragma unroll
    for (int ni = 0; ni < 4; ++ni)
        #pragma unroll
        for (int r = 0; r < 4; ++r) {
            int t = t0 + lg * 4 + r;
            AO[((size_t)b * NTOK + t) * INNER + h * HD + ni * 16 + lr] =
                f2b(acc[ni][r] / lfin[r]);
        }
}

// ---------------------------------------------------------------------------
extern "C" void kernel_launch(void* const* d_in, const int* in_sizes, int n_in,
                              void* d_out, int out_size, void* d_ws, size_t ws_size,
                              hipStream_t stream) {
    const float* x       = (const float*)d_in[0];
    const float* context = (const float*)d_in[1];
    const float* gamma   = (const float*)d_in[2];
    const float* beta    = (const float*)d_in[3];
    const float* Wq      = (const float*)d_in[4];
    const float* Wk      = (const float*)d_in[5];
    const float* Wv      = (const float*)d_in[6];
    const float* Wo      = (const float*)d_in[7];
    const float* bo      = (const float*)d_in[8];
    float* out = (float*)d_out;

    char* p = (char*)d_ws;
    float2* parts = (float2*)p;          p += 1024 * sizeof(float2);
    bf16_t* xn   = (bf16_t*)p;           p += (size_t)B * NTOK * C * 2;      // 8 MB
    bf16_t* Wqt  = (bf16_t*)p;           p += (size_t)INNER * C * 2;
    bf16_t* Wkvt = (bf16_t*)p;           p += (size_t)2 * INNER * CDIM * 2;
    bf16_t* Wot  = (bf16_t*)p;           p += (size_t)C * INNER * 2;
    bf16_t* qb   = (bf16_t*)p;           p += (size_t)B * NH * NTOK * HD * 2;
    bf16_t* kb   = (bf16_t*)p;           p += (size_t)B * NH * CTX * HD * 2;
    bf16_t* vb   = (bf16_t*)p;           p += (size_t)B * NH * CTX * HD * 2; // V^T [b,h,d,key]
    bf16_t* ao   = (bf16_t*)p;           p += (size_t)B * NTOK * INNER * 2;

    hipLaunchKernelGGL(gn_partial_kernel, dim3(B * C), dim3(256), 0, stream, x, parts);
    hipLaunchKernelGGL(gn_apply_kernel, dim3(NTOK / 32, C / 32, B), dim3(256), 0, stream,
                       x, parts, gamma, beta, xn);
    hipLaunchKernelGGL(wcast_all_kernel, dim3(24, 16, 4), dim3(256), 0, stream,
                       Wq, Wk, Wv, Wo, Wqt, Wkvt, Wot);
    // Q = xn @ Wq, pre-scaled by HD^-0.5 * log2(e)  (M=8192, K=512, N=512)
    hipLaunchKernelGGL((gemm_qkv_kernel<0>), dim3(128, 8), dim3(256), 0, stream,
                       (const void*)xn, Wqt, qb, qb, C, 12, 0.125f * LOG2E, 0);
    // K|V = ctx @ [Wk|Wv]; A staged from fp32 directly; V written transposed
    hipLaunchKernelGGL((gemm_qkv_kernel<1>), dim3(32, 16), dim3(256), 0, stream,
                       (const void*)context, Wkvt, kb, vb, CDIM, 10, 1.0f, 1);
    hipLaunchKernelGGL(attn_kernel, dim3(B * NH * (NTOK / 64)), dim3(256), 0, stream,
                       qb, kb, vb, ao);
    hipLaunchKernelGGL(gemm_o_kernel, dim3(128, 8), dim3(256), 0, stream,
                       ao, Wot, bo, x, out);
}

// Round 9
// 163.287 us; speedup vs baseline: 9.2741x; 1.0504x over previous
//
#include <hip/hip_runtime.h>
#include <hip/hip_bf16.h>

#define B 2
#define C 512
#define NTOK 4096          // d*w*hs
#define GROUPS 32
#define CPG 16
#define CTX 1024
#define CDIM 768
#define NH 8
#define HD 64
#define INNER 512
#define EPS 1e-5f
#define KVBLK 64
#define NCH (CTX / KVBLK)  // 16
#define LOG2E 1.44269504f

typedef unsigned short bf16_t;
typedef __attribute__((ext_vector_type(8))) short bf16x8;   // 8 bf16 = 4 VGPRs (MFMA A/B frag)
typedef __attribute__((ext_vector_type(4))) float f32x4;    // MFMA C/D frag

__device__ __forceinline__ bf16_t f2b(float f) {
    unsigned u = __float_as_uint(f);
    u += 0x7fffu + ((u >> 16) & 1u);          // RNE
    return (bf16_t)(u >> 16);
}

// pack 8 fp32 -> 8 bf16 in a float4-sized container (for 16B LDS stores)
__device__ __forceinline__ float4 pack8(const float* v) {
    union { ushort s[8]; float4 f; } u;
    #pragma unroll
    for (int j = 0; j < 8; ++j) u.s[j] = f2b(v[j]);
    return u.f;
}

// v_cvt_pk_bf16_f32: D[15:0]=bf16(lo), D[31:16]=bf16(hi)  (guide T12)
__device__ __forceinline__ unsigned cvtpk(float lo, float hi) {
    unsigned r;
    asm("v_cvt_pk_bf16_f32 %0, %1, %2" : "=v"(r) : "v"(lo), "v"(hi));
    return r;
}

// XOR-swizzle for 64-col bf16 LDS tiles (row stride 128 B).
__device__ __forceinline__ int swz(int row, int col) {
    return row * 64 + (col ^ ((row & 7) << 3));
}

// ---------------------------------------------------------------------------
// Fused prep: blocks [0, B*C) do GroupNorm channel partials; blocks beyond do
// the 4 weight transpose+casts (z = id/384: Wq, Wk, Wv, Wo).
__global__ __launch_bounds__(256) void prep_kernel(
    const float* __restrict__ x, float2* __restrict__ partials,
    const float* __restrict__ Wq, const float* __restrict__ Wk,
    const float* __restrict__ Wv, const float* __restrict__ Wo,
    bf16_t* __restrict__ Wqt, bf16_t* __restrict__ Wkvt, bf16_t* __restrict__ Wot) {
    int blk = blockIdx.x;
    if (blk < B * C) {                    // GN partial: one channel each
        const float* base = x + (size_t)blk * 4096;
        float s = 0.f, ss = 0.f;
        #pragma unroll
        for (int i = 0; i < 4; ++i) {
            float4 v = *(const float4*)&base[(threadIdx.x + i * 256) * 4];
            s += v.x + v.y + v.z + v.w;
            ss += v.x * v.x + v.y * v.y + v.z * v.z + v.w * v.w;
        }
        #pragma unroll
        for (int o = 32; o > 0; o >>= 1) { s += __shfl_xor(s, o); ss += __shfl_xor(ss, o); }
        __shared__ float ls[2][4];
        int wv = threadIdx.x >> 6, ln = threadIdx.x & 63;
        if (ln == 0) { ls[0][wv] = s; ls[1][wv] = ss; }
        __syncthreads();
        if (threadIdx.x == 0)
            partials[blk] = make_float2(ls[0][0] + ls[0][1] + ls[0][2] + ls[0][3],
                                        ls[1][0] + ls[1][1] + ls[1][2] + ls[1][3]);
        return;
    }
    int id = blk - B * C;                 // weight transpose+cast
    int z = id / 384;                     // 384 = 24*16 blocks per matrix
    int rem = id - z * 384;
    int k0 = (rem % 24) * 32, n0 = (rem / 24) * 32;
    const float* in; bf16_t* out; int K;
    if (z == 0)      { in = Wq; out = Wqt;  K = C; }
    else if (z == 1) { in = Wk; out = Wkvt; K = CDIM; }
    else if (z == 2) { in = Wv; out = Wkvt + (size_t)INNER * CDIM; K = CDIM; }
    else             { in = Wo; out = Wot;  K = INNER; }
    if (k0 >= K) return;
    __shared__ float t[32][33];
    int xx = threadIdx.x & 31, yy = threadIdx.x >> 5;
    #pragma unroll
    for (int i = 0; i < 4; ++i)
        t[yy + 8 * i][xx] = in[(size_t)(k0 + yy + 8 * i) * INNER + n0 + xx];
    __syncthreads();
    #pragma unroll
    for (int i = 0; i < 4; ++i)
        out[(size_t)(n0 + yy + 8 * i) * K + k0 + xx] = f2b(t[xx][yy + 8 * i]);
}

// ---------------------------------------------------------------------------
// Apply GroupNorm + transpose to bf16 xn[b][t][c]; finalizes group stats from
// the per-channel partials.
__global__ __launch_bounds__(256) void gn_apply_kernel(const float* __restrict__ x,
                                                       const float2* __restrict__ partials,
                                                       const float* __restrict__ gamma,
                                                       const float* __restrict__ beta,
                                                       bf16_t* __restrict__ xn) {
    __shared__ float tile[32][33];
    __shared__ float gmu[2], grs[2];
    int b = blockIdx.z;
    int c0 = blockIdx.y * 32;
    int t0 = blockIdx.x * 32;
    int tid = threadIdx.x;
    if (tid < 32) {
        int gi = tid >> 4, pi = tid & 15;
        float2 pp = partials[b * C + c0 + gi * 16 + pi];
        float s = pp.x, ss = pp.y;
        #pragma unroll
        for (int o = 8; o > 0; o >>= 1) { s += __shfl_xor(s, o); ss += __shfl_xor(ss, o); }
        if (pi == 0) {
            float mu = s / (float)(CPG * NTOK);
            float var = ss / (float)(CPG * NTOK) - mu * mu;
            gmu[gi] = mu;
            grs[gi] = rsqrtf(var + EPS);
        }
    }
    int tt = tid & 31, cr = tid >> 5;
    __syncthreads();
    #pragma unroll
    for (int i = 0; i < 4; ++i) {
        int co = cr + 8 * i;
        int c = c0 + co;
        float mu = gmu[co >> 4], rs = grs[co >> 4];
        float v = x[((size_t)(b * C + c)) * NTOK + t0 + tt];
        tile[co][tt] = (v - mu) * rs * gamma[c] + beta[c];
    }
    __syncthreads();
    #pragma unroll
    for (int i = 0; i < 4; ++i) {
        int t = t0 + cr + 8 * i;
        int c = c0 + tt;
        xn[((size_t)b * NTOK + t) * C + c] = f2b(tile[tt][cr + 8 * i]);
    }
}

// ---------------------------------------------------------------------------
// MFMA GEMM, 64x64 tile, 4 waves (2x2), BK=64 (2 k-halves per barrier pair):
// 8 MFMA / 8 ds_read / 4 global loads per iter, 2 barriers per 64-K.
// C = A[M][K] @ Bt[N][K]^T.  AFP32: A is fp32 (context), cast during staging.
template <int AFP32>
__global__ __launch_bounds__(256) void gemm_qkv_kernel(
    const void* __restrict__ Av, const bf16_t* __restrict__ Bt,
    bf16_t* __restrict__ outK, bf16_t* __restrict__ outV,
    int K, int seqshift, float oscale, int vtrans) {
    __shared__ __align__(16) bf16_t As[2][64][40];   // [ks half][row][col]
    __shared__ __align__(16) bf16_t Bs[2][64][40];
    const int tid = threadIdx.x;
    const int l = tid & 63, w = tid >> 6;
    const int wr = w >> 1, wc = w & 1;
    const int lg = l >> 4, lr = l & 15;
    const int m0 = blockIdx.x * 64, n0 = blockIdx.y * 64;
    const int rowS = tid >> 2, c8 = (tid & 3) * 8;
    const bf16_t* pa16 = AFP32 ? nullptr : (const bf16_t*)Av + (size_t)(m0 + rowS) * K + c8;
    const float*  pa32 = AFP32 ? (const float*)Av + (size_t)(m0 + rowS) * K + c8 : nullptr;
    const bf16_t* pb = Bt + (size_t)(n0 + rowS) * K + c8;
    f32x4 acc[2][2] = {};
    float av[8];
    float4 ra0, ra1, rb0, rb1;
    #define LOADA(dst, off) do { \
        if (AFP32) { \
            *(float4*)&av[0] = *(const float4*)(pa32 + (off)); \
            *(float4*)&av[4] = *(const float4*)(pa32 + (off) + 4); \
            dst = pack8(av); \
        } else { dst = *(const float4*)(pa16 + (off)); } } while (0)
    LOADA(ra0, 0);
    LOADA(ra1, 32);
    rb0 = *(const float4*)pb;
    rb1 = *(const float4*)(pb + 32);
    *(float4*)&As[0][rowS][c8] = ra0;
    *(float4*)&As[1][rowS][c8] = ra1;
    *(float4*)&Bs[0][rowS][c8] = rb0;
    *(float4*)&Bs[1][rowS][c8] = rb1;
    const int NIT = K >> 6;
    for (int it = 0; it < NIT; ++it) {
        __syncthreads();                            // tile it staged
        if (it + 1 < NIT) {                         // prefetch tile it+1
            int k1 = (it + 1) << 6;
            LOADA(ra0, k1);
            LOADA(ra1, k1 + 32);
            rb0 = *(const float4*)(pb + k1);
            rb1 = *(const float4*)(pb + k1 + 32);
        }
        bf16x8 af[2][2], bfm[2][2];
        #pragma unroll
        for (int ks = 0; ks < 2; ++ks) {
            af[0][ks]  = *(bf16x8*)&As[ks][wr * 32 + lr][lg * 8];
            af[1][ks]  = *(bf16x8*)&As[ks][wr * 32 + 16 + lr][lg * 8];
            bfm[0][ks] = *(bf16x8*)&Bs[ks][wc * 32 + lr][lg * 8];
            bfm[1][ks] = *(bf16x8*)&Bs[ks][wc * 32 + 16 + lr][lg * 8];
        }
        #pragma unroll
        for (int ks = 0; ks < 2; ++ks)
            #pragma unroll
            for (int mi = 0; mi < 2; ++mi)
                #pragma unroll
                for (int ni = 0; ni < 2; ++ni)
                    acc[mi][ni] = __builtin_amdgcn_mfma_f32_16x16x32_bf16(
                        af[mi][ks], bfm[ni][ks], acc[mi][ni], 0, 0, 0);
        __syncthreads();                            // reads of tile it done
        if (it + 1 < NIT) {
            *(float4*)&As[0][rowS][c8] = ra0;
            *(float4*)&As[1][rowS][c8] = ra1;
            *(float4*)&Bs[0][rowS][c8] = rb0;
            *(float4*)&Bs[1][rowS][c8] = rb1;
        }
    }
    #undef LOADA
    const int seqmask = (1 << seqshift) - 1;
    #pragma unroll
    for (int ni = 0; ni < 2; ++ni) {
        int n = n0 + wc * 32 + ni * 16 + lr;
        int nn = n & (INNER - 1);
        int h = nn >> 6, dd = nn & 63;
        bool isV = (n >= INNER);
        #pragma unroll
        for (int mi = 0; mi < 2; ++mi) {
            int mb = m0 + wr * 32 + mi * 16 + lg * 4;
            int bidx = mb >> seqshift, seqb = mb & seqmask;
            if (isV && vtrans) {
                ushort4 pv;                          // 4 consecutive seq packed
                pv.x = f2b(acc[mi][ni][0] * oscale);
                pv.y = f2b(acc[mi][ni][1] * oscale);
                pv.z = f2b(acc[mi][ni][2] * oscale);
                pv.w = f2b(acc[mi][ni][3] * oscale);
                *(ushort4*)&outV[((size_t)(bidx * NH + h) * HD + dd) * (size_t)(seqmask + 1) + seqb] = pv;
            } else {
                bf16_t* dst = isV ? outV : outK;
                #pragma unroll
                for (int r = 0; r < 4; ++r)
                    dst[(((size_t)(bidx * NH + h) << seqshift) + seqb + r) * HD + dd] =
                        f2b(acc[mi][ni][r] * oscale);
            }
        }
    }
}

// O-projection GEMM (K=512), same BK=64 structure; epilogue bias + residual
// + transpose to fp32 out[b][c][t] with float4 stores.
__global__ __launch_bounds__(256) void gemm_o_kernel(
    const bf16_t* __restrict__ A, const bf16_t* __restrict__ Bt,
    const float* __restrict__ bo, const float* __restrict__ x,
    float* __restrict__ out) {
    __shared__ __align__(16) bf16_t As[2][64][40];
    __shared__ __align__(16) bf16_t Bs[2][64][40];
    const int tid = threadIdx.x;
    const int l = tid & 63, w = tid >> 6;
    const int wr = w >> 1, wc = w & 1;
    const int lg = l >> 4, lr = l & 15;
    const int m0 = blockIdx.x * 64, n0 = blockIdx.y * 64;
    const int rowS = tid >> 2, c8 = (tid & 3) * 8;
    const bf16_t* pa = A  + (size_t)(m0 + rowS) * INNER + c8;
    const bf16_t* pb = Bt + (size_t)(n0 + rowS) * INNER + c8;
    f32x4 acc[2][2] = {};
    float4 ra0 = *(const float4*)pa;
    float4 ra1 = *(const float4*)(pa + 32);
    float4 rb0 = *(const float4*)pb;
    float4 rb1 = *(const float4*)(pb + 32);
    *(float4*)&As[0][rowS][c8] = ra0;
    *(float4*)&As[1][rowS][c8] = ra1;
    *(float4*)&Bs[0][rowS][c8] = rb0;
    *(float4*)&Bs[1][rowS][c8] = rb1;
    const int NIT = INNER >> 6;                     // 8
    for (int it = 0; it < NIT; ++it) {
        __syncthreads();
        if (it + 1 < NIT) {
            int k1 = (it + 1) << 6;
            ra0 = *(const float4*)(pa + k1);
            ra1 = *(const float4*)(pa + k1 + 32);
            rb0 = *(const float4*)(pb + k1);
            rb1 = *(const float4*)(pb + k1 + 32);
        }
        bf16x8 af[2][2], bfm[2][2];
        #pragma unroll
        for (int ks = 0; ks < 2; ++ks) {
            af[0][ks]  = *(bf16x8*)&As[ks][wr * 32 + lr][lg * 8];
            af[1][ks]  = *(bf16x8*)&As[ks][wr * 32 + 16 + lr][lg * 8];
            bfm[0][ks] = *(bf16x8*)&Bs[ks][wc * 32 + lr][lg * 8];
            bfm[1][ks] = *(bf16x8*)&Bs[ks][wc * 32 + 16 + lr][lg * 8];
        }
        #pragma unroll
        for (int ks = 0; ks < 2; ++ks)
            #pragma unroll
            for (int mi = 0; mi < 2; ++mi)
                #pragma unroll
                for (int ni = 0; ni < 2; ++ni)
                    acc[mi][ni] = __builtin_amdgcn_mfma_f32_16x16x32_bf16(
                        af[mi][ks], bfm[ni][ks], acc[mi][ni], 0, 0, 0);
        __syncthreads();
        if (it + 1 < NIT) {
            *(float4*)&As[0][rowS][c8] = ra0;
            *(float4*)&As[1][rowS][c8] = ra1;
            *(float4*)&Bs[0][rowS][c8] = rb0;
            *(float4*)&Bs[1][rowS][c8] = rb1;
        }
    }
    #pragma unroll
    for (int mi = 0; mi < 2; ++mi) {
        int mb = m0 + wr * 32 + mi * 16 + lg * 4;   // 4 consecutive t
        int t = mb & (NTOK - 1);
        int bb = mb >> 12;
        #pragma unroll
        for (int ni = 0; ni < 2; ++ni) {
            int cc = n0 + wc * 32 + ni * 16 + lr;
            size_t o = (((size_t)(bb * C + cc)) << 12) + t;
            float4 xr = *(const float4*)&x[o];
            float bias = bo[cc];
            float4 ov;
            ov.x = acc[mi][ni][0] + bias + xr.x;
            ov.y = acc[mi][ni][1] + bias + xr.y;
            ov.z = acc[mi][ni][2] + bias + xr.z;
            ov.w = acc[mi][ni][3] + bias + xr.w;
            *(float4*)&out[o] = ov;
        }
    }
}

// ---------------------------------------------------------------------------
// Flash attention with swapped QK^T (S^T = mfma(K, Q)): per-lane q-row (q=lr),
// in-lane row reduce + 2 shfls, cvt_pk packed P (b64 writes), b128 PV reads.
// 4 waves x 16 q-rows; K [bh][key][d], V pre-transposed [bh][d][key];
// swizzled LDS; reg-prefetch; Q pre-scaled by HD^-0.5*log2(e) (exp2 softmax).
__global__ __launch_bounds__(256) void attn_kernel(
    const bf16_t* __restrict__ Q, const bf16_t* __restrict__ Kb,
    const bf16_t* __restrict__ Vt, bf16_t* __restrict__ AO) {
    __shared__ __align__(16) bf16_t Ks[64 * 64];    // [key][d] swizzled, 8 KB
    __shared__ __align__(16) bf16_t Vs[64 * 64];    // [d][key] swizzled, 8 KB
    __shared__ __align__(16) bf16_t Ps[4][16 * 64]; // per-wave P [q][key] swz, 8 KB
    const int tid = threadIdx.x;
    const int l = tid & 63, w = tid >> 6;
    const int lg = l >> 4, lr = l & 15;
    const int bh = blockIdx.x >> 6;                 // b*8+h
    const int tile = blockIdx.x & 63;
    const int b = bh >> 3, h = bh & 7;
    const int t0 = tile * 64 + w * 16;

    const bf16_t* qbase = Q + ((size_t)bh * NTOK + t0 + lr) * HD;
    bf16x8 qf[2];
    qf[0] = *(const bf16x8*)&qbase[lg * 8];
    qf[1] = *(const bf16x8*)&qbase[32 + lg * 8];

    f32x4 acc[4] = {};          // acc[ni][r] = O[q=4*lg+r][d=ni*16+lr]
    float mrow = -1e30f;        // running max for q = lr (scalar per lane)
    float lrow = 0.f;           // running denom for q = lr

    const bf16_t* kbase = Kb + (size_t)bh * CTX * HD;
    const bf16_t* vbase = Vt + (size_t)bh * HD * CTX;
    const int srow = tid >> 3, sc8 = (tid & 7) * 8;

    float4 kr0 = *(const float4*)&kbase[(size_t)srow * HD + sc8];
    float4 kr1 = *(const float4*)&kbase[(size_t)(srow + 32) * HD + sc8];
    float4 vr0 = *(const float4*)&vbase[(size_t)srow * CTX + sc8];
    float4 vr1 = *(const float4*)&vbase[(size_t)(srow + 32) * CTX + sc8];
    *(float4*)&Ks[swz(srow, sc8)] = kr0;
    *(float4*)&Ks[swz(srow + 32, sc8)] = kr1;
    *(float4*)&Vs[swz(srow, sc8)] = vr0;
    *(float4*)&Vs[swz(srow + 32, sc8)] = vr1;

    for (int c = 0; c < NCH; ++c) {
        __syncthreads();                            // chunk c staged
        if (c + 1 < NCH) {                          // prefetch chunk c+1 to regs
            int k1 = (c + 1) * KVBLK;
            kr0 = *(const float4*)&kbase[(size_t)(k1 + srow) * HD + sc8];
            kr1 = *(const float4*)&kbase[(size_t)(k1 + srow + 32) * HD + sc8];
            vr0 = *(const float4*)&vbase[(size_t)srow * CTX + k1 + sc8];
            vr1 = *(const float4*)&vbase[(size_t)(srow + 32) * CTX + k1 + sc8];
        }
        // Swapped QK^T: sf[ni][r] = S[q=lr][key = ni*16 + 4*lg + r]
        f32x4 sf[4] = {};
        #pragma unroll
        for (int ks = 0; ks < 2; ++ks)
            #pragma unroll
            for (int ni = 0; ni < 4; ++ni) {
                bf16x8 kf = *(bf16x8*)&Ks[swz(ni * 16 + lr, ks * 32 + lg * 8)];
                sf[ni] = __builtin_amdgcn_mfma_f32_16x16x32_bf16(kf, qf[ks], sf[ni], 0, 0, 0);
            }
        // Row reduce: in-lane over 16 values, then across the 4 lg-groups.
        float cm = sf[0][0];
        #pragma unroll
        for (int ni = 0; ni < 4; ++ni)
            #pragma unroll
            for (int r = 0; r < 4; ++r) cm = fmaxf(cm, sf[ni][r]);
        cm = fmaxf(cm, __shfl_xor(cm, 16));
        cm = fmaxf(cm, __shfl_xor(cm, 32));
        float mn = fmaxf(mrow, cm);
        float scl = __builtin_amdgcn_exp2f(mrow - mn);
        mrow = mn;
        float p[4][4];
        float rs = 0.f;
        #pragma unroll
        for (int ni = 0; ni < 4; ++ni)
            #pragma unroll
            for (int r = 0; r < 4; ++r) {
                p[ni][r] = __builtin_amdgcn_exp2f(sf[ni][r] - mn);
                rs += p[ni][r];
            }
        rs += __shfl_xor(rs, 16);
        rs += __shfl_xor(rs, 32);
        lrow = lrow * scl + rs;
        // P -> LDS: keys 4*lg+r are adjacent -> pack pairs, one b64 per ni.
        #pragma unroll
        for (int ni = 0; ni < 4; ++ni) {
            unsigned pk0 = cvtpk(p[ni][0], p[ni][1]);
            unsigned pk1 = cvtpk(p[ni][2], p[ni][3]);
            *(uint2*)&Ps[w][swz(lr, ni * 16 + 4 * lg)] = make_uint2(pk0, pk1);
        }
        // Rescale acc rows (q=4*lg+r) with scl fetched from lane lr=4*lg+r.
        float sclr[4];
        #pragma unroll
        for (int r = 0; r < 4; ++r)
            sclr[r] = __shfl(scl, (l & 48) | (4 * lg + r));
        #pragma unroll
        for (int ni = 0; ni < 4; ++ni)
            #pragma unroll
            for (int r = 0; r < 4; ++r) acc[ni][r] *= sclr[r];
        // PV: A-frag = P[q=lr][keys ks*32+8*lg..+7] (b128), B-frag = V^T.
        #pragma unroll
        for (int ks = 0; ks < 2; ++ks) {
            bf16x8 pf = *(bf16x8*)&Ps[w][swz(lr, ks * 32 + 8 * lg)];
            #pragma unroll
            for (int ni = 0; ni < 4; ++ni) {
                bf16x8 vf = *(bf16x8*)&Vs[swz(ni * 16 + lr, ks * 32 + lg * 8)];
                acc[ni] = __builtin_amdgcn_mfma_f32_16x16x32_bf16(pf, vf, acc[ni], 0, 0, 0);
            }
        }
        __syncthreads();                            // all reads of chunk c done
        if (c + 1 < NCH) {
            *(float4*)&Ks[swz(srow, sc8)] = kr0;
            *(float4*)&Ks[swz(srow + 32, sc8)] = kr1;
            *(float4*)&Vs[swz(srow, sc8)] = vr0;
            *(float4*)&Vs[swz(srow + 32, sc8)] = vr1;
        }
    }

    // Final normalize via v_rcp (lrow for q=4*lg+r lives on lane lr=4*lg+r).
    float linv[4];
    #pragma unroll
    for (int r = 0; r < 4; ++r)
        linv[r] = __builtin_amdgcn_rcpf(__shfl(lrow, (l & 48) | (4 * lg + r)));
    #pragma unroll
    for (int ni = 0; ni < 4; ++ni)
        #pragma unroll
        for (int r = 0; r < 4; ++r) {
            int t = t0 + lg * 4 + r;
            AO[((size_t)b * NTOK + t) * INNER + h * HD + ni * 16 + lr] =
                f2b(acc[ni][r] * linv[r]);
        }
}

// ---------------------------------------------------------------------------
extern "C" void kernel_launch(void* const* d_in, const int* in_sizes, int n_in,
                              void* d_out, int out_size, void* d_ws, size_t ws_size,
                              hipStream_t stream) {
    const float* x       = (const float*)d_in[0];
    const float* context = (const float*)d_in[1];
    const float* gamma   = (const float*)d_in[2];
    const float* beta    = (const float*)d_in[3];
    const float* Wq      = (const float*)d_in[4];
    const float* Wk      = (const float*)d_in[5];
    const float* Wv      = (const float*)d_in[6];
    const float* Wo      = (const float*)d_in[7];
    const float* bo      = (const float*)d_in[8];
    float* out = (float*)d_out;

    char* p = (char*)d_ws;
    float2* parts = (float2*)p;          p += 1024 * sizeof(float2);
    bf16_t* xn   = (bf16_t*)p;           p += (size_t)B * NTOK * C * 2;      // 8 MB
    bf16_t* Wqt  = (bf16_t*)p;           p += (size_t)INNER * C * 2;
    bf16_t* Wkvt = (bf16_t*)p;           p += (size_t)2 * INNER * CDIM * 2;
    bf16_t* Wot  = (bf16_t*)p;           p += (size_t)C * INNER * 2;
    bf16_t* qb   = (bf16_t*)p;           p += (size_t)B * NH * NTOK * HD * 2;
    bf16_t* kb   = (bf16_t*)p;           p += (size_t)B * NH * CTX * HD * 2;
    bf16_t* vb   = (bf16_t*)p;           p += (size_t)B * NH * CTX * HD * 2; // V^T [b,h,d,key]
    bf16_t* ao   = (bf16_t*)p;           p += (size_t)B * NTOK * INNER * 2;

    // prep: 1024 GN-partial blocks + 1536 weight-cast blocks
    hipLaunchKernelGGL(prep_kernel, dim3(B * C + 1536), dim3(256), 0, stream,
                       x, parts, Wq, Wk, Wv, Wo, Wqt, Wkvt, Wot);
    hipLaunchKernelGGL(gn_apply_kernel, dim3(NTOK / 32, C / 32, B), dim3(256), 0, stream,
                       x, parts, gamma, beta, xn);
    // Q = xn @ Wq, pre-scaled by HD^-0.5 * log2(e)  (M=8192, K=512, N=512)
    hipLaunchKernelGGL((gemm_qkv_kernel<0>), dim3(128, 8), dim3(256), 0, stream,
                       (const void*)xn, Wqt, qb, qb, C, 12, 0.125f * LOG2E, 0);
    // K|V = ctx @ [Wk|Wv]; A staged from fp32 directly; V written transposed
    hipLaunchKernelGGL((gemm_qkv_kernel<1>), dim3(32, 16), dim3(256), 0, stream,
                       (const void*)context, Wkvt, kb, vb, CDIM, 10, 1.0f, 1);
    hipLaunchKernelGGL(attn_kernel, dim3(B * NH * (NTOK / 64)), dim3(256), 0, stream,
                       qb, kb, vb, ao);
    hipLaunchKernelGGL(gemm_o_kernel, dim3(128, 8), dim3(256), 0, stream,
                       ao, Wot, bo, x, out);
}